// Round 6
// baseline (305.251 us; speedup 1.0000x reference)
//
#include <hip/hip_runtime.h>
#include <hip/hip_bf16.h>

#define NN 8192
#define EE 262144
#define DD 256
#define FF 512
#define MM 256

typedef __attribute__((ext_vector_type(8))) short short8v;
typedef __attribute__((ext_vector_type(4))) float float4v;
typedef __attribute__((ext_vector_type(16))) float float16v;

__device__ __forceinline__ ushort f2bf(float x) {
  union { float f; unsigned u; } c; c.f = x;
  unsigned r = (c.u + 0x7FFF + ((c.u >> 16) & 1)) >> 16;
  return (ushort)r;
}
__device__ __forceinline__ float b2f(ushort u) {
  union { unsigned u; float f; } c; c.u = ((unsigned)u) << 16;
  return c.f;
}
__device__ __forceinline__ void async_copy16(void* lds, const void* g) {
  __builtin_amdgcn_global_load_lds(
      (const __attribute__((address_space(1))) void*)g,
      (__attribute__((address_space(3))) void*)lds, 16, 0, 0);
}

// ---------------- CSR build ----------------
__global__ void init_kernel(int* degi, int* cursor) {
  int i = blockIdx.x * blockDim.x + threadIdx.x;
  if (i < NN) { degi[i] = 0; cursor[i] = 0; }
}

__global__ void count_kernel(const int* __restrict__ ei, int* __restrict__ degi) {
  int i = blockIdx.x * blockDim.x + threadIdx.x;
  if (i < EE) atomicAdd(&degi[ei[EE + i]], 1);
}

__global__ __launch_bounds__(1024) void scan_kernel(const int* __restrict__ degi,
                                                    int* __restrict__ csr_off,
                                                    float* __restrict__ dinv) {
  __shared__ int part[1024];
  int tid = threadIdx.x;
  int base = tid * 8;
  int loc[8], dv[8]; int s = 0;
#pragma unroll
  for (int i = 0; i < 8; ++i) { int d = degi[base + i]; dv[i] = d; loc[i] = s; s += d; }
  part[tid] = s;
  __syncthreads();
  for (int off = 1; off < 1024; off <<= 1) {
    int v = (tid >= off) ? part[tid - off] : 0;
    __syncthreads();
    part[tid] += v;
    __syncthreads();
  }
  int pre = (tid == 0) ? 0 : part[tid - 1];
#pragma unroll
  for (int i = 0; i < 8; ++i) {
    csr_off[base + i] = pre + loc[i];
    dinv[base + i] = rsqrtf((float)(dv[i] + 1));  // +1 self loop
  }
  if (tid == 1023) csr_off[NN] = part[1023];
}

__global__ void fill_kernel(const int* __restrict__ ei, const int* __restrict__ csr_off,
                            int* __restrict__ cursor, int* __restrict__ csr_src) {
  int i = blockIdx.x * blockDim.x + threadIdx.x;
  if (i < EE) {
    int d = ei[EE + i];
    int pos = csr_off[d] + atomicAdd(&cursor[d], 1);
    csr_src[pos] = ei[i];
  }
}

// ---------------- fused precompute: converts + RF folds ----------------
#define QSCALE 0.090168441f   // log2(e) / 16
#define P1B 9985              // ceil(2556160 / 256)
__global__ __launch_bounds__(256) void prep_kernel(
    const float* __restrict__ h, const float* __restrict__ W_gcn,
    const float* __restrict__ Wv, const float* __restrict__ Wo,
    const float* __restrict__ W1, const float* __restrict__ W2,
    const float* __restrict__ bv,
    const float* __restrict__ Wq, const float* __restrict__ Wk,
    const float* __restrict__ bq, const float* __restrict__ bk,
    const float* __restrict__ RF,
    ushort* __restrict__ hb, ushort* __restrict__ WgcnT, ushort* __restrict__ Wcat,
    ushort* __restrict__ WoT, ushort* __restrict__ W1T, ushort* __restrict__ W2T,
    float* __restrict__ bcat)
{
  __shared__ float wrow[DD];
  if (blockIdx.x < P1B) {
    int i = blockIdx.x * 256 + threadIdx.x;
    const int R0 = NN * DD;
    const int R1 = R0 + DD * DD;
    const int R2 = R1 + DD * DD;
    const int R3 = R2 + DD * DD;
    const int R4 = R3 + DD * FF;
    const int R5 = R4 + FF * DD;
    const int R6 = R5 + DD;
    if (i < R0) {
      int row = i >> 8, col = i & 255;
      hb[(row << 8) | (col ^ ((row & 7) << 3))] = f2bf(h[i]);
    } else if (i < R1) {
      int j = i - R0; int n = j >> 8, k = j & 255;
      WgcnT[(n << 8) | (k ^ ((n & 7) << 3))] = f2bf(W_gcn[k * DD + n]);
    } else if (i < R2) {
      int j = i - R1; int n = j >> 8, k = j & 255;
      Wcat[((512 + n) << 8) | (k ^ ((n & 7) << 3))] = f2bf(Wv[k * DD + n]);
    } else if (i < R3) {
      int j = i - R2; int n = j >> 8, k = j & 255;
      WoT[(n << 8) | (k ^ ((n & 7) << 3))] = f2bf(Wo[k * DD + n]);
    } else if (i < R4) {
      int j = i - R3; int n = j >> 8, k = j & 255;
      W1T[(n << 8) | (k ^ ((n & 7) << 3))] = f2bf(W1[k * FF + n]);
    } else if (i < R5) {
      int j = i - R4; int n = j >> 9, k = j & 511;
      W2T[n * FF + (k ^ ((n & 7) << 3))] = f2bf(W2[k * DD + n]);
    } else if (i < R6) {
      bcat[512 + (i - R5)] = bv[i - R5];
    }
  } else {
    const int b = blockIdx.x - P1B;   // 0..513
    const int m = threadIdx.x;
    if (b < 512) {
      const int d = b & 255;
      const float* W = (b < 256) ? Wq : Wk;
      const float alpha = (b < 256) ? QSCALE : 1.0f;
      wrow[m] = W[d * DD + m];
      __syncthreads();
      float s = 0.0f;
      for (int j = 0; j < DD; ++j) s = fmaf(RF[m * DD + j], wrow[j], s);
      s *= alpha;
      const int row = (b < 256) ? m : (256 + m);
      Wcat[(row << 8) | (d ^ ((m & 7) << 3))] = f2bf(s);
    } else {
      const float* bvec = (b == 512) ? bq : bk;
      const float alpha = (b == 512) ? QSCALE : 1.0f;
      float s = 0.0f;
      for (int j = 0; j < DD; ++j) s = fmaf(bvec[j], RF[m * DD + j], s);
      bcat[((b == 512) ? 0 : 256) + m] = s * alpha;
    }
  }
}

// ---------------- MFMA GEMM: C[M][N] = act(A @ BT^T + bias) ----------------
// OMODE: 0 = f32 out; 1 = bf16 swizzled; 3 = qkv route (qb PLAIN, kb sw, vbT^T); 4 = bf16 plain
template<int OMODE, bool RELU>
__global__ __launch_bounds__(256) void gemm_bf16_kernel(
    const ushort* __restrict__ A, const ushort* __restrict__ BT,
    const float* __restrict__ bias, void* __restrict__ Cv,
    void* __restrict__ Cv2, void* __restrict__ Cv3,
    int M, int N, int K)
{
  __shared__ ushort As[2][4096];
  __shared__ ushort Bs[2][4096];
  const int tid = threadIdx.x;
  const int l = tid & 63;
  const int wv = tid >> 6;
  const int lr = l & 15, lg = l >> 4;
  const int m0 = blockIdx.y * 64, n0 = blockIdx.x * 64;
  const int wm = (wv >> 1) * 32, wn = (wv & 1) * 32;
  const int r0 = tid >> 3, r1 = 32 + (tid >> 3);
  const int co = (tid & 7) << 3;
  float4v acc[2][2];
#pragma unroll
  for (int mt = 0; mt < 2; ++mt)
#pragma unroll
    for (int nt = 0; nt < 2; ++nt) acc[mt][nt] = (float4v){0.f, 0.f, 0.f, 0.f};

#define GSTAGE(b, k0) { \
    async_copy16(&As[b][(r0 << 6) + co], &A[(size_t)(m0 + r0) * K + (k0) + co]); \
    async_copy16(&As[b][(r1 << 6) + co], &A[(size_t)(m0 + r1) * K + (k0) + co]); \
    async_copy16(&Bs[b][(r0 << 6) + co], &BT[(size_t)(n0 + r0) * K + (k0) + co]); \
    async_copy16(&Bs[b][(r1 << 6) + co], &BT[(size_t)(n0 + r1) * K + (k0) + co]); }

  GSTAGE(0, 0)
  const int nk = K >> 6;
  for (int kt = 0; kt < nk; ++kt) {
    asm volatile("s_waitcnt vmcnt(0)" ::: "memory");
    __syncthreads();
    if (kt + 1 < nk) GSTAGE((kt + 1) & 1, (kt + 1) << 6)
    const ushort* as_ = As[kt & 1];
    const ushort* bs_ = Bs[kt & 1];
    __builtin_amdgcn_s_setprio(1);
#pragma unroll
    for (int h = 0; h < 2; ++h) {
      const int swo = (((h << 2) + lg) ^ (lr & 7)) << 3;
      short8v af[2], bfr[2];
#pragma unroll
      for (int mt = 0; mt < 2; ++mt)
        af[mt] = *(const short8v*)&as_[((wm + (mt << 4) + lr) << 6) + swo];
#pragma unroll
      for (int nt = 0; nt < 2; ++nt)
        bfr[nt] = *(const short8v*)&bs_[((wn + (nt << 4) + lr) << 6) + swo];
#pragma unroll
      for (int mt = 0; mt < 2; ++mt)
#pragma unroll
        for (int nt = 0; nt < 2; ++nt)
          acc[mt][nt] = __builtin_amdgcn_mfma_f32_16x16x32_bf16(af[mt], bfr[nt], acc[mt][nt], 0, 0, 0);
    }
    __builtin_amdgcn_s_setprio(0);
  }
#pragma unroll
  for (int nt = 0; nt < 2; ++nt) {
    const int col = n0 + wn + (nt << 4) + lr;
    const float bv = bias ? bias[col] : 0.0f;
#pragma unroll
    for (int mt = 0; mt < 2; ++mt)
#pragma unroll
      for (int r = 0; r < 4; ++r) {
        const int m = m0 + wm + (mt << 4) + (lg << 2) + r;
        float v = acc[mt][nt][r] + bv;
        if (RELU) v = fmaxf(v, 0.0f);
        if (OMODE == 0) {
          ((float*)Cv)[(size_t)m * N + col] = v;
        } else if (OMODE == 1) {
          ((ushort*)Cv)[(size_t)m * N + (col ^ ((m & 7) << 3))] = f2bf(v);
        } else if (OMODE == 4) {
          ((ushort*)Cv)[(size_t)m * N + col] = f2bf(v);
        } else {  // qkv route
          if (col < 256) ((ushort*)Cv)[(size_t)m * 256 + col] = f2bf(v);                         // qb plain
          else if (col < 512) ((ushort*)Cv2)[(size_t)m * 256 + ((col - 256) ^ ((m & 7) << 3))] = f2bf(v);
          else ((ushort*)Cv3)[(size_t)(col - 512) * NN + m] = f2bf(v);
        }
      }
  }
#undef GSTAGE
}

// ---------------- GCN gather + residual + LN1 (xw in bf16) ----------------
__global__ __launch_bounds__(256) void gcn_gather_ln_kernel(
    const ushort* __restrict__ xwb, const float* __restrict__ h,
    const float* __restrict__ dinv, const int* __restrict__ csr_off,
    const int* __restrict__ csr_src, const float* __restrict__ b_gcn,
    const float* __restrict__ g1, const float* __restrict__ be1,
    float* __restrict__ h1, ushort* __restrict__ h1b)
{
  __shared__ float2 red[256];
  const int node = blockIdx.x;
  const int c = threadIdx.x;
  const float di = dinv[node];
  const int e0 = csr_off[node], e1 = csr_off[node + 1];
  float acc = 0.0f;
  for (int e = e0; e < e1; ++e) {
    int s = csr_src[e];
    acc = fmaf(b2f(xwb[(size_t)s * DD + c]), dinv[s], acc);
  }
  float y = fmaf(acc, di, b2f(xwb[(size_t)node * DD + c]) * di * di);
  y += b_gcn[c];
  y += h[node * DD + c];
  red[c] = make_float2(y, y * y);
  __syncthreads();
  for (int sft = 128; sft > 0; sft >>= 1) {
    if (c < sft) { red[c].x += red[c + sft].x; red[c].y += red[c + sft].y; }
    __syncthreads();
  }
  float mu = red[0].x * (1.0f / 256.0f);
  float var = red[0].y * (1.0f / 256.0f) - mu * mu;
  float inv = rsqrtf(fmaxf(var, 0.0f) + 1e-5f);
  float v = (y - mu) * inv * g1[c] + be1[c];
  h1[node * DD + c] = v;
  h1b[(node << 8) | (c ^ ((node & 7) << 3))] = f2bf(v);
}

// ---------------- residual + LN ----------------
__global__ __launch_bounds__(256) void ln_res_kernel(
    const float* __restrict__ a, const float* __restrict__ b,
    const float* __restrict__ g, const float* __restrict__ be,
    float* __restrict__ out, ushort* __restrict__ outb)
{
  __shared__ float2 red[256];
  const int row = blockIdx.x;
  const int c = threadIdx.x;
  float y = a[row * DD + c] + b[row * DD + c];
  red[c] = make_float2(y, y * y);
  __syncthreads();
  for (int sft = 128; sft > 0; sft >>= 1) {
    if (c < sft) { red[c].x += red[c + sft].x; red[c].y += red[c + sft].y; }
    __syncthreads();
  }
  float mu = red[0].x * (1.0f / 256.0f);
  float var = red[0].y * (1.0f / 256.0f) - mu * mu;
  float inv = rsqrtf(fmaxf(var, 0.0f) + 1e-5f);
  float v = (y - mu) * inv * g[c] + be[c];
  out[row * DD + c] = v;
  if (outb) outb[(row << 8) | (c ^ ((row & 7) << 3))] = f2bf(v);
}

// ---------------- MFMA flash attention (32x32 QK, no-max softmax) ----------------
// 128 q-rows/block (4 waves x 32). S = mfma(K, Q) 32x32x16 -> lane holds 16 scores
// of q-col (l&31). Scores are bounded (|s_log2| <~ 9) so softmax uses NO running max:
// p = exp2(s) raw, l deferred to epilogue. P -> PV A-frag via 8 cvt_pk + 4
// permlane32_swap (zero bpermute). K LDS row-XOR swizzled; V slot ^ (d&3) via
// pre-swizzled DMA source (rule 21). Single barrier/iter, counted prefetch.
__global__ __launch_bounds__(256, 2) void flash_mfma_kernel(
    const ushort* __restrict__ qb, const ushort* __restrict__ kb,
    const ushort* __restrict__ vbT, ushort* __restrict__ opb,
    float* __restrict__ ml, int ksn, int kchunk)
{
  __shared__ ushort Kbuf[2][8192];   // [key 32][m 256] stored-swizzled (from kb)
  __shared__ ushort Vbuf[2][8192];   // [d 256][key 32], 16B-slot ^ (d&3)

  const int tid = threadIdx.x;
  const int l = tid & 63, wv = tid >> 6;
  const int c32 = l & 31, hi = l >> 5;
  const int qt = blockIdx.x / ksn, ks = blockIdx.x % ksn;  // ks = bid%8 -> per-XCD KV chunk
  const int q0 = qt * 128;
  const int kbase = ks * kchunk;

  // staging source pointers (strength-reduced; advance per iter)
  const int vrow = tid >> 2;
  const ushort* kptr = kb + (size_t)(kbase + (tid >> 5)) * 256 + ((tid & 31) << 3);
  const ushort* vptr = vbT + (size_t)vrow * NN + kbase + (((tid & 3) ^ (vrow & 3)) << 3);

#define FSTAGE(b) { \
    _Pragma("unroll") \
    for (int c = 0; c < 4; ++c) { \
      async_copy16(&Kbuf[b][((c << 8) + tid) << 3], kptr + (size_t)c * (8 * 256)); \
      async_copy16(&Vbuf[b][((c << 8) + tid) << 3], vptr + (size_t)c * (64 * NN)); \
    } }

  FSTAGE(0)

  // Q fragments: 32 q-rows/wave, lane (q=c32) holds k-slice hi*8 of each 16-k block
  short8v qfr[16];
  {
    const ushort* qrow = qb + (size_t)(q0 + wv * 32 + c32) * 256 + (hi << 3);
#pragma unroll
    for (int kk = 0; kk < 16; ++kk)
      qfr[kk] = *(const short8v*)(qrow + (kk << 4));
  }

  float16v acc[8];
#pragma unroll
  for (int dt = 0; dt < 8; ++dt) acc[dt] = (float16v)(0.0f);
  float lsum = 0.f;

  const int nit = kchunk >> 5;
  for (int it = 0; it < nit; ++it) {
    asm volatile("s_waitcnt vmcnt(0)" ::: "memory");
    __syncthreads();
    if (it + 1 < nit) {
      kptr += 32 * 256;
      vptr += 32;
      FSTAGE((it + 1) & 1)
    }
    const ushort* Kp = Kbuf[it & 1];
    const ushort* Vp = Vbuf[it & 1];

    // ---- S[key][q] = K @ Q^T (32x32, k=256) ----
    float16v s = (float16v)(0.0f);
    __builtin_amdgcn_s_setprio(1);
#pragma unroll
    for (int kk = 0; kk < 16; ++kk) {
      short8v kf = *(const short8v*)&Kp[(c32 << 8) + (((kk << 4) + (hi << 3)) ^ ((c32 & 7) << 3))];
      s = __builtin_amdgcn_mfma_f32_32x32x16_bf16(kf, qfr[kk], s, 0, 0, 0);
    }
    __builtin_amdgcn_s_setprio(0);

    // ---- p = exp2(s), deferred l, P->A-frag via cvt_pk + permlane32_swap ----
    float p[16];
#pragma unroll
    for (int r = 0; r < 16; ++r) { p[r] = exp2f(s[r]); lsum += p[r]; }
    unsigned u0, u1, u2, u3, u4, u5, u6, u7;
    asm("v_cvt_pk_bf16_f32 %0, %1, %2" : "=v"(u0) : "v"(p[0]),  "v"(p[1]));
    asm("v_cvt_pk_bf16_f32 %0, %1, %2" : "=v"(u1) : "v"(p[2]),  "v"(p[3]));
    asm("v_cvt_pk_bf16_f32 %0, %1, %2" : "=v"(u2) : "v"(p[4]),  "v"(p[5]));
    asm("v_cvt_pk_bf16_f32 %0, %1, %2" : "=v"(u3) : "v"(p[6]),  "v"(p[7]));
    asm("v_cvt_pk_bf16_f32 %0, %1, %2" : "=v"(u4) : "v"(p[8]),  "v"(p[9]));
    asm("v_cvt_pk_bf16_f32 %0, %1, %2" : "=v"(u5) : "v"(p[10]), "v"(p[11]));
    asm("v_cvt_pk_bf16_f32 %0, %1, %2" : "=v"(u6) : "v"(p[12]), "v"(p[13]));
    asm("v_cvt_pk_bf16_f32 %0, %1, %2" : "=v"(u7) : "v"(p[14]), "v"(p[15]));
    // keys (r&3)+8*(r>>2)+4hi: words u0..u3 = key-pairs (0,1)(2,3)(8,9)(10,11)+4hi; u4..u7 same +16
    asm volatile("v_permlane32_swap_b32 %0, %1" : "+v"(u0), "+v"(u2));
    asm volatile("v_permlane32_swap_b32 %0, %1" : "+v"(u1), "+v"(u3));
    asm volatile("v_permlane32_swap_b32 %0, %1" : "+v"(u4), "+v"(u6));
    asm volatile("v_permlane32_swap_b32 %0, %1" : "+v"(u5), "+v"(u7));
    union { unsigned uu[4]; short8v v; } P0, P1;
    P0.uu[0] = u0; P0.uu[1] = u1; P0.uu[2] = u2; P0.uu[3] = u3;  // keys kt=0 (0..15)
    P1.uu[0] = u4; P1.uu[1] = u5; P1.uu[2] = u6; P1.uu[3] = u7;  // keys kt=1 (16..31)

    // ---- O[q][d] += P @ V (8 x 32x32x16, 2 k-halves) ----
    __builtin_amdgcn_s_setprio(1);
#pragma unroll
    for (int dt = 0; dt < 8; ++dt) {
      const int drow = (dt << 5) + c32;
      short8v vf0 = *(const short8v*)&Vp[(drow << 5) + ((hi ^ (drow & 3)) << 3)];
      short8v vf1 = *(const short8v*)&Vp[(drow << 5) + (((2 + hi) ^ (drow & 3)) << 3)];
      acc[dt] = __builtin_amdgcn_mfma_f32_32x32x16_bf16(P0.v, vf0, acc[dt], 0, 0, 0);
      acc[dt] = __builtin_amdgcn_mfma_f32_32x32x16_bf16(P1.v, vf1, acc[dt], 0, 0, 0);
    }
    __builtin_amdgcn_s_setprio(0);
  }
#undef FSTAGE

  // ---- epilogue: l reduce (one shfl) + bf16 partial store ----
  float lt = lsum + __shfl_xor(lsum, 32);
  if (hi == 0) ml[(size_t)ks * NN + q0 + wv * 32 + c32] = lt;
  ushort* op = opb + (size_t)ks * (NN * DD);
#pragma unroll
  for (int dt = 0; dt < 8; ++dt)
#pragma unroll
    for (int r = 0; r < 16; ++r) {
      const int qrow = q0 + wv * 32 + (r & 3) + ((r >> 2) << 3) + (hi << 2);
      op[(size_t)qrow * DD + (dt << 5) + c32] = f2bf(acc[dt][r]);
    }
}

__global__ __launch_bounds__(256) void flash_merge_kernel(
    const ushort* __restrict__ opb, const float* __restrict__ ml,
    ushort* __restrict__ hgb, int ksn)
{
  const int row = blockIdx.x;
  const int c = threadIdx.x;
  float num = 0.f, L = 0.f;
  for (int i = 0; i < ksn; ++i) {
    L += ml[(size_t)i * NN + row];
    num += b2f(opb[(size_t)i * NN * DD + (size_t)row * DD + c]);
  }
  hgb[(row << 8) | (c ^ ((row & 7) << 3))] = f2bf(num / L);
}

extern "C" void kernel_launch(void* const* d_in, const int* in_sizes, int n_in,
                              void* d_out, int out_size, void* d_ws, size_t ws_size,
                              hipStream_t stream) {
  (void)in_sizes; (void)n_in; (void)out_size;
  const float* h     = (const float*)d_in[0];
  const int*   ei    = (const int*)  d_in[1];
  const float* W_gcn = (const float*)d_in[2];
  const float* b_gcn = (const float*)d_in[3];
  const float* Wq    = (const float*)d_in[4];
  const float* bq    = (const float*)d_in[5];
  const float* Wk    = (const float*)d_in[6];
  const float* bk    = (const float*)d_in[7];
  const float* Wv    = (const float*)d_in[8];
  const float* bv    = (const float*)d_in[9];
  const float* Wo    = (const float*)d_in[10];
  const float* bo    = (const float*)d_in[11];
  const float* RF    = (const float*)d_in[12];
  const float* g1    = (const float*)d_in[13];
  const float* be1   = (const float*)d_in[14];
  const float* g2    = (const float*)d_in[15];
  const float* be2   = (const float*)d_in[16];
  const float* g3    = (const float*)d_in[17];
  const float* be3   = (const float*)d_in[18];
  const float* W1    = (const float*)d_in[19];
  const float* b1    = (const float*)d_in[20];
  const float* W2    = (const float*)d_in[21];
  const float* b2    = (const float*)d_in[22];
  float* out = (float*)d_out;

  const size_t M2 = (size_t)NN * DD;
  const int ksn = (ws_size >= (size_t)64 * 1024 * 1024) ? 8 : 4;
  const int kchunk = NN / ksn;

  char* base = (char*)d_ws;
  float*  h1   = (float*)base;  base += M2 * 4;
  ushort* hbX  = (ushort*)base; base += M2 * 2;   // hb, later hgb
  ushort* h1bX = (ushort*)base; base += M2 * 2;   // h1b, later h2b
  ushort* qb   = (ushort*)base; base += M2 * 2;
  ushort* kb   = (ushort*)base; base += M2 * 2;
  ushort* vbT  = (ushort*)base; base += M2 * 2;
  ushort* opb  = (ushort*)base;
  float*  R    = (float*)opb;   base += (size_t)ksn * M2 * 2;
  float*  mlf  = (float*)base;  base += (size_t)8 * NN * 4;
  ushort* WgcnT = (ushort*)base; base += DD * DD * 2;
  ushort* Wcat  = (ushort*)base; base += (size_t)768 * DD * 2;
  ushort* WoT   = (ushort*)base; base += DD * DD * 2;
  ushort* W1T   = (ushort*)base; base += FF * DD * 2;
  ushort* W2T   = (ushort*)base; base += DD * FF * 2;
  float*  bcat  = (float*)base;  base += 768 * 4;
  float*  dinv  = (float*)base;  base += NN * 4;
  int* degi    = (int*)base; base += NN * 4;
  int* cursor  = (int*)base; base += NN * 4;
  int* csr_off = (int*)base; base += (NN + 4) * 4;
  int* csr_src = (int*)base; base += EE * 4;

  // aliases
  ushort* xwb = (ushort*)R;        // bf16 xw, pre-flash (R region is opb during flash)
  float*  hgo = R;                 // post-merge
  float*  h2  = R + M2;            // post-merge
  ushort* tb  = qb;                // spans qb+kb, post-flash (8192x512 bf16)
  float*  f2  = h1;                // post-LN2 (h1 dead after LN2)
  ushort* hgb = hbX;
  ushort* h2b = h1bX;

  // CSR build
  init_kernel<<<NN / 256, 256, 0, stream>>>(degi, cursor);
  count_kernel<<<EE / 256, 256, 0, stream>>>(ei, degi);
  scan_kernel<<<1, 1024, 0, stream>>>(degi, csr_off, dinv);
  fill_kernel<<<EE / 256, 256, 0, stream>>>(ei, csr_off, cursor, csr_src);

  // fused precompute
  prep_kernel<<<P1B + 514, 256, 0, stream>>>(
      h, W_gcn, Wv, Wo, W1, W2, bv, Wq, Wk, bq, bk, RF,
      hbX, WgcnT, Wcat, WoT, W1T, W2T, bcat);

  // xw = h @ W_gcn (bf16 plain out -> L2-resident gather source)
  gemm_bf16_kernel<4, false><<<dim3(DD / 64, NN / 64), 256, 0, stream>>>(
      hbX, WgcnT, nullptr, xwb, nullptr, nullptr, NN, DD, DD);
  // local GCN + LN1
  gcn_gather_ln_kernel<<<NN, 256, 0, stream>>>(xwb, h, dinv, csr_off, csr_src, b_gcn, g1, be1, h1, h1bX);
  // fused q/k/v projections (single GEMM, routed epilogue)
  gemm_bf16_kernel<3, false><<<dim3(768 / 64, NN / 64), 256, 0, stream>>>(
      h1bX, Wcat, bcat, qb, kb, vbT, NN, 768, DD);
  // attention
  flash_mfma_kernel<<<(NN / 128) * ksn, 256, 0, stream>>>(qb, kb, vbT, opb, mlf, ksn, kchunk);
  flash_merge_kernel<<<NN, 256, 0, stream>>>(opb, mlf, hgb, ksn);
  // output projection + LN2
  gemm_bf16_kernel<0, false><<<dim3(DD / 64, NN / 64), 256, 0, stream>>>(
      hgb, WoT, bo, hgo, nullptr, nullptr, NN, DD, DD);
  ln_res_kernel<<<NN, 256, 0, stream>>>(h1, hgo, g2, be2, h2, h2b);
  // FFN + LN3
  gemm_bf16_kernel<1, true ><<<dim3(FF / 64, NN / 64), 256, 0, stream>>>(
      h2b, W1T, b1, tb, nullptr, nullptr, NN, FF, DD);
  gemm_bf16_kernel<0, false><<<dim3(DD / 64, NN / 64), 256, 0, stream>>>(
      tb, W2T, b2, f2, nullptr, nullptr, NN, DD, FF);
  ln_res_kernel<<<NN, 256, 0, stream>>>(h2, f2, g3, be3, out, nullptr);
}

// Round 7
// 301.722 us; speedup vs baseline: 1.0117x; 1.0117x over previous
//
#include <hip/hip_runtime.h>
#include <hip/hip_bf16.h>

#define NN 8192
#define EE 262144
#define DD 256
#define FF 512
#define MM 256

typedef __attribute__((ext_vector_type(8))) short short8v;
typedef __attribute__((ext_vector_type(4))) float float4v;
typedef __attribute__((ext_vector_type(16))) float float16v;

__device__ __forceinline__ ushort f2bf(float x) {
  union { float f; unsigned u; } c; c.f = x;
  unsigned r = (c.u + 0x7FFF + ((c.u >> 16) & 1)) >> 16;
  return (ushort)r;
}
__device__ __forceinline__ float b2f(ushort u) {
  union { unsigned u; float f; } c; c.u = ((unsigned)u) << 16;
  return c.f;
}
__device__ __forceinline__ void async_copy16(void* lds, const void* g) {
  __builtin_amdgcn_global_load_lds(
      (const __attribute__((address_space(1))) void*)g,
      (__attribute__((address_space(3))) void*)lds, 16, 0, 0);
}

// ---------------- CSR build ----------------
__global__ void init_kernel(int* degi, int* cursor) {
  int i = blockIdx.x * blockDim.x + threadIdx.x;
  if (i < NN) { degi[i] = 0; cursor[i] = 0; }
}

__global__ void count_kernel(const int* __restrict__ ei, int* __restrict__ degi) {
  int i = blockIdx.x * blockDim.x + threadIdx.x;
  if (i < EE) atomicAdd(&degi[ei[EE + i]], 1);
}

__global__ __launch_bounds__(1024) void scan_kernel(const int* __restrict__ degi,
                                                    int* __restrict__ csr_off,
                                                    float* __restrict__ dinv) {
  __shared__ int part[1024];
  int tid = threadIdx.x;
  int base = tid * 8;
  int loc[8], dv[8]; int s = 0;
#pragma unroll
  for (int i = 0; i < 8; ++i) { int d = degi[base + i]; dv[i] = d; loc[i] = s; s += d; }
  part[tid] = s;
  __syncthreads();
  for (int off = 1; off < 1024; off <<= 1) {
    int v = (tid >= off) ? part[tid - off] : 0;
    __syncthreads();
    part[tid] += v;
    __syncthreads();
  }
  int pre = (tid == 0) ? 0 : part[tid - 1];
#pragma unroll
  for (int i = 0; i < 8; ++i) {
    csr_off[base + i] = pre + loc[i];
    dinv[base + i] = rsqrtf((float)(dv[i] + 1));  // +1 self loop
  }
  if (tid == 1023) csr_off[NN] = part[1023];
}

__global__ void fill_kernel(const int* __restrict__ ei, const int* __restrict__ csr_off,
                            int* __restrict__ cursor, int* __restrict__ csr_src) {
  int i = blockIdx.x * blockDim.x + threadIdx.x;
  if (i < EE) {
    int d = ei[EE + i];
    int pos = csr_off[d] + atomicAdd(&cursor[d], 1);
    csr_src[pos] = ei[i];
  }
}

// ---------------- fused precompute: converts + RF folds ----------------
#define QSCALE 0.090168441f   // log2(e) / 16
#define P1B 9985              // ceil(2556160 / 256)
__global__ __launch_bounds__(256) void prep_kernel(
    const float* __restrict__ h, const float* __restrict__ W_gcn,
    const float* __restrict__ Wv, const float* __restrict__ Wo,
    const float* __restrict__ W1, const float* __restrict__ W2,
    const float* __restrict__ bv,
    const float* __restrict__ Wq, const float* __restrict__ Wk,
    const float* __restrict__ bq, const float* __restrict__ bk,
    const float* __restrict__ RF,
    ushort* __restrict__ hb, ushort* __restrict__ WgcnT, ushort* __restrict__ Wcat,
    ushort* __restrict__ WoT, ushort* __restrict__ W1T, ushort* __restrict__ W2T,
    float* __restrict__ bcat)
{
  __shared__ float wrow[DD];
  if (blockIdx.x < P1B) {
    int i = blockIdx.x * 256 + threadIdx.x;
    const int R0 = NN * DD;
    const int R1 = R0 + DD * DD;
    const int R2 = R1 + DD * DD;
    const int R3 = R2 + DD * DD;
    const int R4 = R3 + DD * FF;
    const int R5 = R4 + FF * DD;
    const int R6 = R5 + DD;
    if (i < R0) {
      int row = i >> 8, col = i & 255;
      hb[(row << 8) | (col ^ ((row & 7) << 3))] = f2bf(h[i]);
    } else if (i < R1) {
      int j = i - R0; int n = j >> 8, k = j & 255;
      WgcnT[(n << 8) | (k ^ ((n & 7) << 3))] = f2bf(W_gcn[k * DD + n]);
    } else if (i < R2) {
      int j = i - R1; int n = j >> 8, k = j & 255;
      Wcat[((512 + n) << 8) | (k ^ ((n & 7) << 3))] = f2bf(Wv[k * DD + n]);
    } else if (i < R3) {
      int j = i - R2; int n = j >> 8, k = j & 255;
      WoT[(n << 8) | (k ^ ((n & 7) << 3))] = f2bf(Wo[k * DD + n]);
    } else if (i < R4) {
      int j = i - R3; int n = j >> 8, k = j & 255;
      W1T[(n << 8) | (k ^ ((n & 7) << 3))] = f2bf(W1[k * FF + n]);
    } else if (i < R5) {
      int j = i - R4; int n = j >> 9, k = j & 511;
      W2T[n * FF + (k ^ ((n & 7) << 3))] = f2bf(W2[k * DD + n]);
    } else if (i < R6) {
      bcat[512 + (i - R5)] = bv[i - R5];
    }
  } else {
    const int b = blockIdx.x - P1B;   // 0..513
    const int m = threadIdx.x;
    if (b < 512) {
      const int d = b & 255;
      const float* W = (b < 256) ? Wq : Wk;
      const float alpha = (b < 256) ? QSCALE : 1.0f;
      wrow[m] = W[d * DD + m];
      __syncthreads();
      float s = 0.0f;
      for (int j = 0; j < DD; ++j) s = fmaf(RF[m * DD + j], wrow[j], s);
      s *= alpha;
      const int row = (b < 256) ? m : (256 + m);
      Wcat[(row << 8) | (d ^ ((m & 7) << 3))] = f2bf(s);
    } else {
      const float* bvec = (b == 512) ? bq : bk;
      const float alpha = (b == 512) ? QSCALE : 1.0f;
      float s = 0.0f;
      for (int j = 0; j < DD; ++j) s = fmaf(bvec[j], RF[m * DD + j], s);
      bcat[((b == 512) ? 0 : 256) + m] = s * alpha;
    }
  }
}

// ---------------- MFMA GEMM: C[M][N] = act(A @ BT^T + bias) ----------------
// OMODE: 0 = f32 out; 1 = bf16 swizzled; 3 = qkv route (qb PLAIN, kb sw, vbT^T); 4 = bf16 plain
template<int OMODE, bool RELU>
__global__ __launch_bounds__(256) void gemm_bf16_kernel(
    const ushort* __restrict__ A, const ushort* __restrict__ BT,
    const float* __restrict__ bias, void* __restrict__ Cv,
    void* __restrict__ Cv2, void* __restrict__ Cv3,
    int M, int N, int K)
{
  __shared__ ushort As[2][4096];
  __shared__ ushort Bs[2][4096];
  const int tid = threadIdx.x;
  const int l = tid & 63;
  const int wv = tid >> 6;
  const int lr = l & 15, lg = l >> 4;
  const int m0 = blockIdx.y * 64, n0 = blockIdx.x * 64;
  const int wm = (wv >> 1) * 32, wn = (wv & 1) * 32;
  const int r0 = tid >> 3, r1 = 32 + (tid >> 3);
  const int co = (tid & 7) << 3;
  float4v acc[2][2];
#pragma unroll
  for (int mt = 0; mt < 2; ++mt)
#pragma unroll
    for (int nt = 0; nt < 2; ++nt) acc[mt][nt] = (float4v){0.f, 0.f, 0.f, 0.f};

#define GSTAGE(b, k0) { \
    async_copy16(&As[b][(r0 << 6) + co], &A[(size_t)(m0 + r0) * K + (k0) + co]); \
    async_copy16(&As[b][(r1 << 6) + co], &A[(size_t)(m0 + r1) * K + (k0) + co]); \
    async_copy16(&Bs[b][(r0 << 6) + co], &BT[(size_t)(n0 + r0) * K + (k0) + co]); \
    async_copy16(&Bs[b][(r1 << 6) + co], &BT[(size_t)(n0 + r1) * K + (k0) + co]); }

  GSTAGE(0, 0)
  const int nk = K >> 6;
  for (int kt = 0; kt < nk; ++kt) {
    asm volatile("s_waitcnt vmcnt(0)" ::: "memory");
    __syncthreads();
    if (kt + 1 < nk) GSTAGE((kt + 1) & 1, (kt + 1) << 6)
    const ushort* as_ = As[kt & 1];
    const ushort* bs_ = Bs[kt & 1];
    __builtin_amdgcn_s_setprio(1);
#pragma unroll
    for (int h = 0; h < 2; ++h) {
      const int swo = (((h << 2) + lg) ^ (lr & 7)) << 3;
      short8v af[2], bfr[2];
#pragma unroll
      for (int mt = 0; mt < 2; ++mt)
        af[mt] = *(const short8v*)&as_[((wm + (mt << 4) + lr) << 6) + swo];
#pragma unroll
      for (int nt = 0; nt < 2; ++nt)
        bfr[nt] = *(const short8v*)&bs_[((wn + (nt << 4) + lr) << 6) + swo];
#pragma unroll
      for (int mt = 0; mt < 2; ++mt)
#pragma unroll
        for (int nt = 0; nt < 2; ++nt)
          acc[mt][nt] = __builtin_amdgcn_mfma_f32_16x16x32_bf16(af[mt], bfr[nt], acc[mt][nt], 0, 0, 0);
    }
    __builtin_amdgcn_s_setprio(0);
  }
#pragma unroll
  for (int nt = 0; nt < 2; ++nt) {
    const int col = n0 + wn + (nt << 4) + lr;
    const float bv = bias ? bias[col] : 0.0f;
#pragma unroll
    for (int mt = 0; mt < 2; ++mt)
#pragma unroll
      for (int r = 0; r < 4; ++r) {
        const int m = m0 + wm + (mt << 4) + (lg << 2) + r;
        float v = acc[mt][nt][r] + bv;
        if (RELU) v = fmaxf(v, 0.0f);
        if (OMODE == 0) {
          ((float*)Cv)[(size_t)m * N + col] = v;
        } else if (OMODE == 1) {
          ((ushort*)Cv)[(size_t)m * N + (col ^ ((m & 7) << 3))] = f2bf(v);
        } else if (OMODE == 4) {
          ((ushort*)Cv)[(size_t)m * N + col] = f2bf(v);
        } else {  // qkv route
          if (col < 256) ((ushort*)Cv)[(size_t)m * 256 + col] = f2bf(v);                         // qb plain
          else if (col < 512) ((ushort*)Cv2)[(size_t)m * 256 + ((col - 256) ^ ((m & 7) << 3))] = f2bf(v);
          else ((ushort*)Cv3)[(size_t)(col - 512) * NN + m] = f2bf(v);
        }
      }
  }
#undef GSTAGE
}

// ---------------- GCN gather + residual + LN1 (xw in bf16) ----------------
__global__ __launch_bounds__(256) void gcn_gather_ln_kernel(
    const ushort* __restrict__ xwb, const float* __restrict__ h,
    const float* __restrict__ dinv, const int* __restrict__ csr_off,
    const int* __restrict__ csr_src, const float* __restrict__ b_gcn,
    const float* __restrict__ g1, const float* __restrict__ be1,
    float* __restrict__ h1, ushort* __restrict__ h1b)
{
  __shared__ float2 red[256];
  const int node = blockIdx.x;
  const int c = threadIdx.x;
  const float di = dinv[node];
  const int e0 = csr_off[node], e1 = csr_off[node + 1];
  float acc = 0.0f;
  for (int e = e0; e < e1; ++e) {
    int s = csr_src[e];
    acc = fmaf(b2f(xwb[(size_t)s * DD + c]), dinv[s], acc);
  }
  float y = fmaf(acc, di, b2f(xwb[(size_t)node * DD + c]) * di * di);
  y += b_gcn[c];
  y += h[node * DD + c];
  red[c] = make_float2(y, y * y);
  __syncthreads();
  for (int sft = 128; sft > 0; sft >>= 1) {
    if (c < sft) { red[c].x += red[c + sft].x; red[c].y += red[c + sft].y; }
    __syncthreads();
  }
  float mu = red[0].x * (1.0f / 256.0f);
  float var = red[0].y * (1.0f / 256.0f) - mu * mu;
  float inv = rsqrtf(fmaxf(var, 0.0f) + 1e-5f);
  float v = (y - mu) * inv * g1[c] + be1[c];
  h1[node * DD + c] = v;
  h1b[(node << 8) | (c ^ ((node & 7) << 3))] = f2bf(v);
}

// ---------------- residual + LN ----------------
__global__ __launch_bounds__(256) void ln_res_kernel(
    const float* __restrict__ a, const float* __restrict__ b,
    const float* __restrict__ g, const float* __restrict__ be,
    float* __restrict__ out, ushort* __restrict__ outb)
{
  __shared__ float2 red[256];
  const int row = blockIdx.x;
  const int c = threadIdx.x;
  float y = a[row * DD + c] + b[row * DD + c];
  red[c] = make_float2(y, y * y);
  __syncthreads();
  for (int sft = 128; sft > 0; sft >>= 1) {
    if (c < sft) { red[c].x += red[c + sft].x; red[c].y += red[c + sft].y; }
    __syncthreads();
  }
  float mu = red[0].x * (1.0f / 256.0f);
  float var = red[0].y * (1.0f / 256.0f) - mu * mu;
  float inv = rsqrtf(fmaxf(var, 0.0f) + 1e-5f);
  float v = (y - mu) * inv * g[c] + be[c];
  out[row * DD + c] = v;
  if (outb) outb[(row << 8) | (c ^ ((row & 7) << 3))] = f2bf(v);
}

// ---------------- MFMA flash attention (32x32 QK, no-max softmax) ----------------
// 128 q-rows/block (4 waves x 32). S = mfma(K, Q) 32x32x16 -> lane holds 16 scores
// of q-col (l&31). Bounded scores -> NO running max: p = exp2(s), l deferred to
// epilogue. P -> PV A-frag via 8 cvt_pk + 4 permlane32_swap. K LDS row-XOR
// swizzled. V 16B-slot ^ ((d>>1)&3) via pre-swizzled DMA source (rule 21):
// group 16*(d&1)+4*slot is then a bijection over 8 bank-groups per 8 rows ->
// conflict-free b128 reads (round-6's (d&3) was 4-way WRONG).
__global__ __launch_bounds__(256, 2) void flash_mfma_kernel(
    const ushort* __restrict__ qb, const ushort* __restrict__ kb,
    const ushort* __restrict__ vbT, ushort* __restrict__ opb,
    float* __restrict__ ml, int ksn, int kchunk)
{
  __shared__ ushort Kbuf[2][8192];   // [key 32][m 256] stored-swizzled (from kb)
  __shared__ ushort Vbuf[2][8192];   // [d 256][key 32], 16B-slot ^ ((d>>1)&3)

  const int tid = threadIdx.x;
  const int l = tid & 63, wv = tid >> 6;
  const int c32 = l & 31, hi = l >> 5;
  const int qt = blockIdx.x / ksn, ks = blockIdx.x % ksn;  // ks = bid%8 -> per-XCD KV chunk
  const int q0 = qt * 128;
  const int kbase = ks * kchunk;

  // staging source pointers (strength-reduced; advance per iter)
  const int vrow = tid >> 2;
  const ushort* kptr = kb + (size_t)(kbase + (tid >> 5)) * 256 + ((tid & 31) << 3);
  const ushort* vptr = vbT + (size_t)vrow * NN + kbase + (((tid & 3) ^ ((vrow >> 1) & 3)) << 3);

#define FSTAGE(b) { \
    _Pragma("unroll") \
    for (int c = 0; c < 4; ++c) { \
      async_copy16(&Kbuf[b][((c << 8) + tid) << 3], kptr + (size_t)c * (8 * 256)); \
      async_copy16(&Vbuf[b][((c << 8) + tid) << 3], vptr + (size_t)c * (64 * NN)); \
    } }

  FSTAGE(0)

  // Q fragments: 32 q-rows/wave, lane (q=c32) holds k-slice hi*8 of each 16-k block
  short8v qfr[16];
  {
    const ushort* qrow = qb + (size_t)(q0 + wv * 32 + c32) * 256 + (hi << 3);
#pragma unroll
    for (int kk = 0; kk < 16; ++kk)
      qfr[kk] = *(const short8v*)(qrow + (kk << 4));
  }

  float16v acc[8];
#pragma unroll
  for (int dt = 0; dt < 8; ++dt) acc[dt] = (float16v)(0.0f);
  float lsum = 0.f;

  // V read-side slot swizzle: logical slots (hi) and (2+hi), phys = logical ^ ((c32>>1)&3)
  const int vsw = (c32 >> 1) & 3;
  const int voff0 = (hi ^ vsw) << 3;
  const int voff1 = ((2 + hi) ^ vsw) << 3;

  const int nit = kchunk >> 5;
  for (int it = 0; it < nit; ++it) {
    asm volatile("s_waitcnt vmcnt(0)" ::: "memory");
    __syncthreads();
    if (it + 1 < nit) {
      kptr += 32 * 256;
      vptr += 32;
      FSTAGE((it + 1) & 1)
    }
    const ushort* Kp = Kbuf[it & 1];
    const ushort* Vp = Vbuf[it & 1];

    // ---- S[key][q] = K @ Q^T (32x32, k=256) ----
    float16v s = (float16v)(0.0f);
    __builtin_amdgcn_s_setprio(1);
#pragma unroll
    for (int kk = 0; kk < 16; ++kk) {
      short8v kf = *(const short8v*)&Kp[(c32 << 8) + (((kk << 4) + (hi << 3)) ^ ((c32 & 7) << 3))];
      s = __builtin_amdgcn_mfma_f32_32x32x16_bf16(kf, qfr[kk], s, 0, 0, 0);
    }
    __builtin_amdgcn_s_setprio(0);

    // ---- p = exp2(s), deferred l, P->A-frag via cvt_pk + permlane32_swap ----
    float p[16];
#pragma unroll
    for (int r = 0; r < 16; ++r) p[r] = exp2f(s[r]);
    {
      float t0 = (p[0] + p[1]) + (p[2] + p[3]);
      float t1 = (p[4] + p[5]) + (p[6] + p[7]);
      float t2 = (p[8] + p[9]) + (p[10] + p[11]);
      float t3 = (p[12] + p[13]) + (p[14] + p[15]);
      lsum += (t0 + t1) + (t2 + t3);
    }
    unsigned u0, u1, u2, u3, u4, u5, u6, u7;
    asm("v_cvt_pk_bf16_f32 %0, %1, %2" : "=v"(u0) : "v"(p[0]),  "v"(p[1]));
    asm("v_cvt_pk_bf16_f32 %0, %1, %2" : "=v"(u1) : "v"(p[2]),  "v"(p[3]));
    asm("v_cvt_pk_bf16_f32 %0, %1, %2" : "=v"(u2) : "v"(p[4]),  "v"(p[5]));
    asm("v_cvt_pk_bf16_f32 %0, %1, %2" : "=v"(u3) : "v"(p[6]),  "v"(p[7]));
    asm("v_cvt_pk_bf16_f32 %0, %1, %2" : "=v"(u4) : "v"(p[8]),  "v"(p[9]));
    asm("v_cvt_pk_bf16_f32 %0, %1, %2" : "=v"(u5) : "v"(p[10]), "v"(p[11]));
    asm("v_cvt_pk_bf16_f32 %0, %1, %2" : "=v"(u6) : "v"(p[12]), "v"(p[13]));
    asm("v_cvt_pk_bf16_f32 %0, %1, %2" : "=v"(u7) : "v"(p[14]), "v"(p[15]));
    asm volatile("v_permlane32_swap_b32 %0, %1" : "+v"(u0), "+v"(u2));
    asm volatile("v_permlane32_swap_b32 %0, %1" : "+v"(u1), "+v"(u3));
    asm volatile("v_permlane32_swap_b32 %0, %1" : "+v"(u4), "+v"(u6));
    asm volatile("v_permlane32_swap_b32 %0, %1" : "+v"(u5), "+v"(u7));
    union { unsigned uu[4]; short8v v; } P0, P1;
    P0.uu[0] = u0; P0.uu[1] = u1; P0.uu[2] = u2; P0.uu[3] = u3;  // keys 0..15
    P1.uu[0] = u4; P1.uu[1] = u5; P1.uu[2] = u6; P1.uu[3] = u7;  // keys 16..31

    // ---- O[q][d] += P @ V (8 x 32x32x16, 2 k-halves) ----
    __builtin_amdgcn_s_setprio(1);
#pragma unroll
    for (int dt = 0; dt < 8; ++dt) {
      const int drow = (dt << 5) + c32;
      short8v vf0 = *(const short8v*)&Vp[(drow << 5) + voff0];
      short8v vf1 = *(const short8v*)&Vp[(drow << 5) + voff1];
      acc[dt] = __builtin_amdgcn_mfma_f32_32x32x16_bf16(P0.v, vf0, acc[dt], 0, 0, 0);
      acc[dt] = __builtin_amdgcn_mfma_f32_32x32x16_bf16(P1.v, vf1, acc[dt], 0, 0, 0);
    }
    __builtin_amdgcn_s_setprio(0);
  }
#undef FSTAGE

  // ---- epilogue: l reduce (one shfl) + bf16 partial store ----
  float lt = lsum + __shfl_xor(lsum, 32);
  if (hi == 0) ml[(size_t)ks * NN + q0 + wv * 32 + c32] = lt;
  ushort* op = opb + (size_t)ks * (NN * DD);
#pragma unroll
  for (int dt = 0; dt < 8; ++dt)
#pragma unroll
    for (int r = 0; r < 16; ++r) {
      const int qrow = q0 + wv * 32 + (r & 3) + ((r >> 2) << 3) + (hi << 2);
      op[(size_t)qrow * DD + (dt << 5) + c32] = f2bf(acc[dt][r]);
    }
}

__global__ __launch_bounds__(256) void flash_merge_kernel(
    const ushort* __restrict__ opb, const float* __restrict__ ml,
    ushort* __restrict__ hgb, int ksn)
{
  const int row = blockIdx.x;
  const int c = threadIdx.x;
  float num = 0.f, L = 0.f;
  for (int i = 0; i < ksn; ++i) {
    L += ml[(size_t)i * NN + row];
    num += b2f(opb[(size_t)i * NN * DD + (size_t)row * DD + c]);
  }
  hgb[(row << 8) | (c ^ ((row & 7) << 3))] = f2bf(num / L);
}

extern "C" void kernel_launch(void* const* d_in, const int* in_sizes, int n_in,
                              void* d_out, int out_size, void* d_ws, size_t ws_size,
                              hipStream_t stream) {
  (void)in_sizes; (void)n_in; (void)out_size;
  const float* h     = (const float*)d_in[0];
  const int*   ei    = (const int*)  d_in[1];
  const float* W_gcn = (const float*)d_in[2];
  const float* b_gcn = (const float*)d_in[3];
  const float* Wq    = (const float*)d_in[4];
  const float* bq    = (const float*)d_in[5];
  const float* Wk    = (const float*)d_in[6];
  const float* bk    = (const float*)d_in[7];
  const float* Wv    = (const float*)d_in[8];
  const float* bv    = (const float*)d_in[9];
  const float* Wo    = (const float*)d_in[10];
  const float* bo    = (const float*)d_in[11];
  const float* RF    = (const float*)d_in[12];
  const float* g1    = (const float*)d_in[13];
  const float* be1   = (const float*)d_in[14];
  const float* g2    = (const float*)d_in[15];
  const float* be2   = (const float*)d_in[16];
  const float* g3    = (const float*)d_in[17];
  const float* be3   = (const float*)d_in[18];
  const float* W1    = (const float*)d_in[19];
  const float* b1    = (const float*)d_in[20];
  const float* W2    = (const float*)d_in[21];
  const float* b2    = (const float*)d_in[22];
  float* out = (float*)d_out;

  const size_t M2 = (size_t)NN * DD;
  const int ksn = (ws_size >= (size_t)64 * 1024 * 1024) ? 8 : 4;
  const int kchunk = NN / ksn;

  char* base = (char*)d_ws;
  float*  h1   = (float*)base;  base += M2 * 4;
  ushort* hbX  = (ushort*)base; base += M2 * 2;   // hb, later hgb
  ushort* h1bX = (ushort*)base; base += M2 * 2;   // h1b, later h2b
  ushort* qb   = (ushort*)base; base += M2 * 2;
  ushort* kb   = (ushort*)base; base += M2 * 2;
  ushort* vbT  = (ushort*)base; base += M2 * 2;
  ushort* opb  = (ushort*)base;
  float*  R    = (float*)opb;   base += (size_t)ksn * M2 * 2;
  float*  mlf  = (float*)base;  base += (size_t)8 * NN * 4;
  ushort* WgcnT = (ushort*)base; base += DD * DD * 2;
  ushort* Wcat  = (ushort*)base; base += (size_t)768 * DD * 2;
  ushort* WoT   = (ushort*)base; base += DD * DD * 2;
  ushort* W1T   = (ushort*)base; base += FF * DD * 2;
  ushort* W2T   = (ushort*)base; base += DD * FF * 2;
  float*  bcat  = (float*)base;  base += 768 * 4;
  float*  dinv  = (float*)base;  base += NN * 4;
  int* degi    = (int*)base; base += NN * 4;
  int* cursor  = (int*)base; base += NN * 4;
  int* csr_off = (int*)base; base += (NN + 4) * 4;
  int* csr_src = (int*)base; base += EE * 4;

  // aliases
  ushort* xwb = (ushort*)R;        // bf16 xw, pre-flash (R region is opb during flash)
  float*  hgo = R;                 // post-merge
  float*  h2  = R + M2;            // post-merge
  ushort* tb  = qb;                // spans qb+kb, post-flash (8192x512 bf16)
  float*  f2  = h1;                // post-LN2 (h1 dead after LN2)
  ushort* hgb = hbX;
  ushort* h2b = h1bX;

  // CSR build
  init_kernel<<<NN / 256, 256, 0, stream>>>(degi, cursor);
  count_kernel<<<EE / 256, 256, 0, stream>>>(ei, degi);
  scan_kernel<<<1, 1024, 0, stream>>>(degi, csr_off, dinv);
  fill_kernel<<<EE / 256, 256, 0, stream>>>(ei, csr_off, cursor, csr_src);

  // fused precompute
  prep_kernel<<<P1B + 514, 256, 0, stream>>>(
      h, W_gcn, Wv, Wo, W1, W2, bv, Wq, Wk, bq, bk, RF,
      hbX, WgcnT, Wcat, WoT, W1T, W2T, bcat);

  // xw = h @ W_gcn (bf16 plain out -> L2-resident gather source)
  gemm_bf16_kernel<4, false><<<dim3(DD / 64, NN / 64), 256, 0, stream>>>(
      hbX, WgcnT, nullptr, xwb, nullptr, nullptr, NN, DD, DD);
  // local GCN + LN1
  gcn_gather_ln_kernel<<<NN, 256, 0, stream>>>(xwb, h, dinv, csr_off, csr_src, b_gcn, g1, be1, h1, h1bX);
  // fused q/k/v projections (single GEMM, routed epilogue)
  gemm_bf16_kernel<3, false><<<dim3(768 / 64, NN / 64), 256, 0, stream>>>(
      h1bX, Wcat, bcat, qb, kb, vbT, NN, 768, DD);
  // attention
  flash_mfma_kernel<<<(NN / 128) * ksn, 256, 0, stream>>>(qb, kb, vbT, opb, mlf, ksn, kchunk);
  flash_merge_kernel<<<NN, 256, 0, stream>>>(opb, mlf, hgb, ksn);
  // output projection + LN2
  gemm_bf16_kernel<0, false><<<dim3(DD / 64, NN / 64), 256, 0, stream>>>(
      hgb, WoT, bo, hgo, nullptr, nullptr, NN, DD, DD);
  ln_res_kernel<<<NN, 256, 0, stream>>>(h1, hgo, g2, be2, h2, h2b);
  // FFN + LN3
  gemm_bf16_kernel<1, true ><<<dim3(FF / 64, NN / 64), 256, 0, stream>>>(
      h2b, W1T, b1, tb, nullptr, nullptr, NN, FF, DD);
  gemm_bf16_kernel<0, false><<<dim3(DD / 64, NN / 64), 256, 0, stream>>>(
      tb, W2T, b2, f2, nullptr, nullptr, NN, DD, FF);
  ln_res_kernel<<<NN, 256, 0, stream>>>(h2, f2, g3, be3, out, nullptr);
}

// Round 8
// 285.832 us; speedup vs baseline: 1.0679x; 1.0556x over previous
//
#include <hip/hip_runtime.h>
#include <hip/hip_bf16.h>

#define NN 8192
#define EE 262144
#define DD 256
#define FF 512
#define MM 256

typedef __attribute__((ext_vector_type(8))) short short8v;
typedef __attribute__((ext_vector_type(4))) float float4v;
typedef __attribute__((ext_vector_type(16))) float float16v;

__device__ __forceinline__ ushort f2bf(float x) {
  union { float f; unsigned u; } c; c.f = x;
  unsigned r = (c.u + 0x7FFF + ((c.u >> 16) & 1)) >> 16;
  return (ushort)r;
}
__device__ __forceinline__ float b2f(ushort u) {
  union { unsigned u; float f; } c; c.u = ((unsigned)u) << 16;
  return c.f;
}
__device__ __forceinline__ void async_copy16(void* lds, const void* g) {
  __builtin_amdgcn_global_load_lds(
      (const __attribute__((address_space(1))) void*)g,
      (__attribute__((address_space(3))) void*)lds, 16, 0, 0);
}

// ---------------- CSR build ----------------
__global__ void init_kernel(int* degi, int* cursor) {
  int i = blockIdx.x * blockDim.x + threadIdx.x;
  if (i < NN) { degi[i] = 0; cursor[i] = 0; }
}

__global__ void count_kernel(const int* __restrict__ ei, int* __restrict__ degi) {
  int i = blockIdx.x * blockDim.x + threadIdx.x;
  if (i < EE) atomicAdd(&degi[ei[EE + i]], 1);
}

__global__ __launch_bounds__(1024) void scan_kernel(const int* __restrict__ degi,
                                                    int* __restrict__ csr_off,
                                                    float* __restrict__ dinv) {
  __shared__ int part[1024];
  int tid = threadIdx.x;
  int base = tid * 8;
  int loc[8], dv[8]; int s = 0;
#pragma unroll
  for (int i = 0; i < 8; ++i) { int d = degi[base + i]; dv[i] = d; loc[i] = s; s += d; }
  part[tid] = s;
  __syncthreads();
  for (int off = 1; off < 1024; off <<= 1) {
    int v = (tid >= off) ? part[tid - off] : 0;
    __syncthreads();
    part[tid] += v;
    __syncthreads();
  }
  int pre = (tid == 0) ? 0 : part[tid - 1];
#pragma unroll
  for (int i = 0; i < 8; ++i) {
    csr_off[base + i] = pre + loc[i];
    dinv[base + i] = rsqrtf((float)(dv[i] + 1));  // +1 self loop
  }
  if (tid == 1023) csr_off[NN] = part[1023];
}

__global__ void fill_kernel(const int* __restrict__ ei, const int* __restrict__ csr_off,
                            int* __restrict__ cursor, int* __restrict__ csr_src) {
  int i = blockIdx.x * blockDim.x + threadIdx.x;
  if (i < EE) {
    int d = ei[EE + i];
    int pos = csr_off[d] + atomicAdd(&cursor[d], 1);
    csr_src[pos] = ei[i];
  }
}

// ---------------- fused precompute: converts + RF folds ----------------
#define QSCALE 0.090168441f   // log2(e) / 16
#define P1B 9985              // ceil(2556160 / 256)
__global__ __launch_bounds__(256) void prep_kernel(
    const float* __restrict__ h, const float* __restrict__ W_gcn,
    const float* __restrict__ Wv, const float* __restrict__ Wo,
    const float* __restrict__ W1, const float* __restrict__ W2,
    const float* __restrict__ bv,
    const float* __restrict__ Wq, const float* __restrict__ Wk,
    const float* __restrict__ bq, const float* __restrict__ bk,
    const float* __restrict__ RF,
    ushort* __restrict__ hb, ushort* __restrict__ WgcnT, ushort* __restrict__ Wcat,
    ushort* __restrict__ WoT, ushort* __restrict__ W1T, ushort* __restrict__ W2T,
    float* __restrict__ bcat)
{
  __shared__ float wrow[DD];
  if (blockIdx.x < P1B) {
    int i = blockIdx.x * 256 + threadIdx.x;
    const int R0 = NN * DD;
    const int R1 = R0 + DD * DD;
    const int R2 = R1 + DD * DD;
    const int R3 = R2 + DD * DD;
    const int R4 = R3 + DD * FF;
    const int R5 = R4 + FF * DD;
    const int R6 = R5 + DD;
    if (i < R0) {
      int row = i >> 8, col = i & 255;
      hb[(row << 8) | (col ^ ((row & 7) << 3))] = f2bf(h[i]);
    } else if (i < R1) {
      int j = i - R0; int n = j >> 8, k = j & 255;
      WgcnT[(n << 8) | (k ^ ((n & 7) << 3))] = f2bf(W_gcn[k * DD + n]);
    } else if (i < R2) {
      int j = i - R1; int n = j >> 8, k = j & 255;
      Wcat[((512 + n) << 8) | (k ^ ((n & 7) << 3))] = f2bf(Wv[k * DD + n]);
    } else if (i < R3) {
      int j = i - R2; int n = j >> 8, k = j & 255;
      WoT[(n << 8) | (k ^ ((n & 7) << 3))] = f2bf(Wo[k * DD + n]);
    } else if (i < R4) {
      int j = i - R3; int n = j >> 8, k = j & 255;
      W1T[(n << 8) | (k ^ ((n & 7) << 3))] = f2bf(W1[k * FF + n]);
    } else if (i < R5) {
      int j = i - R4; int n = j >> 9, k = j & 511;
      W2T[n * FF + (k ^ ((n & 7) << 3))] = f2bf(W2[k * DD + n]);
    } else if (i < R6) {
      bcat[512 + (i - R5)] = bv[i - R5];
    }
  } else {
    const int b = blockIdx.x - P1B;   // 0..513
    const int m = threadIdx.x;
    if (b < 512) {
      const int d = b & 255;
      const float* W = (b < 256) ? Wq : Wk;
      const float alpha = (b < 256) ? QSCALE : 1.0f;
      wrow[m] = W[d * DD + m];
      __syncthreads();
      float s = 0.0f;
      for (int j = 0; j < DD; ++j) s = fmaf(RF[m * DD + j], wrow[j], s);
      s *= alpha;
      const int row = (b < 256) ? m : (256 + m);
      Wcat[(row << 8) | (d ^ ((m & 7) << 3))] = f2bf(s);
    } else {
      const float* bvec = (b == 512) ? bq : bk;
      const float alpha = (b == 512) ? QSCALE : 1.0f;
      float s = 0.0f;
      for (int j = 0; j < DD; ++j) s = fmaf(bvec[j], RF[m * DD + j], s);
      bcat[((b == 512) ? 0 : 256) + m] = s * alpha;
    }
  }
}

// ---------------- MFMA GEMM: C[M][N] = act(A @ BT^T + bias) ----------------
// OMODE: 0 = f32 out; 1 = bf16 swizzled; 3 = qkv route (qb PLAIN, kb sw, vbT^T); 4 = bf16 plain
template<int OMODE, bool RELU>
__global__ __launch_bounds__(256) void gemm_bf16_kernel(
    const ushort* __restrict__ A, const ushort* __restrict__ BT,
    const float* __restrict__ bias, void* __restrict__ Cv,
    void* __restrict__ Cv2, void* __restrict__ Cv3,
    int M, int N, int K)
{
  __shared__ ushort As[2][4096];
  __shared__ ushort Bs[2][4096];
  const int tid = threadIdx.x;
  const int l = tid & 63;
  const int wv = tid >> 6;
  const int lr = l & 15, lg = l >> 4;
  const int m0 = blockIdx.y * 64, n0 = blockIdx.x * 64;
  const int wm = (wv >> 1) * 32, wn = (wv & 1) * 32;
  const int r0 = tid >> 3, r1 = 32 + (tid >> 3);
  const int co = (tid & 7) << 3;
  float4v acc[2][2];
#pragma unroll
  for (int mt = 0; mt < 2; ++mt)
#pragma unroll
    for (int nt = 0; nt < 2; ++nt) acc[mt][nt] = (float4v){0.f, 0.f, 0.f, 0.f};

#define GSTAGE(b, k0) { \
    async_copy16(&As[b][(r0 << 6) + co], &A[(size_t)(m0 + r0) * K + (k0) + co]); \
    async_copy16(&As[b][(r1 << 6) + co], &A[(size_t)(m0 + r1) * K + (k0) + co]); \
    async_copy16(&Bs[b][(r0 << 6) + co], &BT[(size_t)(n0 + r0) * K + (k0) + co]); \
    async_copy16(&Bs[b][(r1 << 6) + co], &BT[(size_t)(n0 + r1) * K + (k0) + co]); }

  GSTAGE(0, 0)
  const int nk = K >> 6;
  for (int kt = 0; kt < nk; ++kt) {
    asm volatile("s_waitcnt vmcnt(0)" ::: "memory");
    __syncthreads();
    if (kt + 1 < nk) GSTAGE((kt + 1) & 1, (kt + 1) << 6)
    const ushort* as_ = As[kt & 1];
    const ushort* bs_ = Bs[kt & 1];
    __builtin_amdgcn_s_setprio(1);
#pragma unroll
    for (int h = 0; h < 2; ++h) {
      const int swo = (((h << 2) + lg) ^ (lr & 7)) << 3;
      short8v af[2], bfr[2];
#pragma unroll
      for (int mt = 0; mt < 2; ++mt)
        af[mt] = *(const short8v*)&as_[((wm + (mt << 4) + lr) << 6) + swo];
#pragma unroll
      for (int nt = 0; nt < 2; ++nt)
        bfr[nt] = *(const short8v*)&bs_[((wn + (nt << 4) + lr) << 6) + swo];
#pragma unroll
      for (int mt = 0; mt < 2; ++mt)
#pragma unroll
        for (int nt = 0; nt < 2; ++nt)
          acc[mt][nt] = __builtin_amdgcn_mfma_f32_16x16x32_bf16(af[mt], bfr[nt], acc[mt][nt], 0, 0, 0);
    }
    __builtin_amdgcn_s_setprio(0);
  }
#pragma unroll
  for (int nt = 0; nt < 2; ++nt) {
    const int col = n0 + wn + (nt << 4) + lr;
    const float bv = bias ? bias[col] : 0.0f;
#pragma unroll
    for (int mt = 0; mt < 2; ++mt)
#pragma unroll
      for (int r = 0; r < 4; ++r) {
        const int m = m0 + wm + (mt << 4) + (lg << 2) + r;
        float v = acc[mt][nt][r] + bv;
        if (RELU) v = fmaxf(v, 0.0f);
        if (OMODE == 0) {
          ((float*)Cv)[(size_t)m * N + col] = v;
        } else if (OMODE == 1) {
          ((ushort*)Cv)[(size_t)m * N + (col ^ ((m & 7) << 3))] = f2bf(v);
        } else if (OMODE == 4) {
          ((ushort*)Cv)[(size_t)m * N + col] = f2bf(v);
        } else {  // qkv route
          if (col < 256) ((ushort*)Cv)[(size_t)m * 256 + col] = f2bf(v);                         // qb plain
          else if (col < 512) ((ushort*)Cv2)[(size_t)m * 256 + ((col - 256) ^ ((m & 7) << 3))] = f2bf(v);
          else ((ushort*)Cv3)[(size_t)(col - 512) * NN + m] = f2bf(v);
        }
      }
  }
#undef GSTAGE
}

// ---------------- GCN gather + residual + LN1 (1 wave/row, vectorized) ----------------
__global__ __launch_bounds__(64) void gcn_gather_ln_kernel(
    const ushort* __restrict__ xwb, const float* __restrict__ h,
    const float* __restrict__ dinv, const int* __restrict__ csr_off,
    const int* __restrict__ csr_src, const float* __restrict__ b_gcn,
    const float* __restrict__ g1, const float* __restrict__ be1,
    float* __restrict__ h1, ushort* __restrict__ h1b)
{
  const int node = blockIdx.x;
  const int t = threadIdx.x;
  const int c4 = t << 2;
  const float di = dinv[node];
  const int e0 = csr_off[node], e1 = csr_off[node + 1];
  float acc[4] = {0.f, 0.f, 0.f, 0.f};
  for (int e = e0; e < e1; ++e) {
    int s = csr_src[e];
    float ds = dinv[s];
    ushort4 xv = *(const ushort4*)&xwb[(size_t)s * DD + c4];
    acc[0] = fmaf(b2f(xv.x), ds, acc[0]);
    acc[1] = fmaf(b2f(xv.y), ds, acc[1]);
    acc[2] = fmaf(b2f(xv.z), ds, acc[2]);
    acc[3] = fmaf(b2f(xv.w), ds, acc[3]);
  }
  ushort4 sv = *(const ushort4*)&xwb[(size_t)node * DD + c4];
  float4 hv = *(const float4*)&h[(size_t)node * DD + c4];
  float4 bg = *(const float4*)&b_gcn[c4];
  const float dii = di * di;
  float y[4];
  y[0] = fmaf(acc[0], di, b2f(sv.x) * dii) + bg.x + hv.x;
  y[1] = fmaf(acc[1], di, b2f(sv.y) * dii) + bg.y + hv.y;
  y[2] = fmaf(acc[2], di, b2f(sv.z) * dii) + bg.z + hv.z;
  y[3] = fmaf(acc[3], di, b2f(sv.w) * dii) + bg.w + hv.w;
  float s1 = (y[0] + y[1]) + (y[2] + y[3]);
  float s2 = (y[0]*y[0] + y[1]*y[1]) + (y[2]*y[2] + y[3]*y[3]);
#pragma unroll
  for (int m = 1; m <= 32; m <<= 1) { s1 += __shfl_xor(s1, m); s2 += __shfl_xor(s2, m); }
  float mu = s1 * (1.0f / 256.0f);
  float var = s2 * (1.0f / 256.0f) - mu * mu;
  float inv = rsqrtf(fmaxf(var, 0.0f) + 1e-5f);
  float4 g4 = *(const float4*)&g1[c4];
  float4 b4 = *(const float4*)&be1[c4];
  float v0 = (y[0] - mu) * inv * g4.x + b4.x;
  float v1 = (y[1] - mu) * inv * g4.y + b4.y;
  float v2 = (y[2] - mu) * inv * g4.z + b4.z;
  float v3 = (y[3] - mu) * inv * g4.w + b4.w;
  *(float4*)&h1[(size_t)node * DD + c4] = make_float4(v0, v1, v2, v3);
  ushort4 ob; ob.x = f2bf(v0); ob.y = f2bf(v1); ob.z = f2bf(v2); ob.w = f2bf(v3);
  *(ushort4*)&h1b[(node << 8) + ((t ^ ((node & 7) << 1)) << 2)] = ob;
}

// ---------------- residual + LN (1 wave/row, vectorized) ----------------
__global__ __launch_bounds__(64) void ln_res_kernel(
    const float* __restrict__ a, const float* __restrict__ b,
    const float* __restrict__ g, const float* __restrict__ be,
    float* __restrict__ out, ushort* __restrict__ outb)
{
  const int row = blockIdx.x;
  const int t = threadIdx.x;
  const int c4 = t << 2;
  float4 av = *(const float4*)&a[(size_t)row * DD + c4];
  float4 bv = *(const float4*)&b[(size_t)row * DD + c4];
  float y[4] = {av.x + bv.x, av.y + bv.y, av.z + bv.z, av.w + bv.w};
  float s1 = (y[0] + y[1]) + (y[2] + y[3]);
  float s2 = (y[0]*y[0] + y[1]*y[1]) + (y[2]*y[2] + y[3]*y[3]);
#pragma unroll
  for (int m = 1; m <= 32; m <<= 1) { s1 += __shfl_xor(s1, m); s2 += __shfl_xor(s2, m); }
  float mu = s1 * (1.0f / 256.0f);
  float var = s2 * (1.0f / 256.0f) - mu * mu;
  float inv = rsqrtf(fmaxf(var, 0.0f) + 1e-5f);
  float4 g4 = *(const float4*)&g[c4];
  float4 b4 = *(const float4*)&be[c4];
  float v0 = (y[0] - mu) * inv * g4.x + b4.x;
  float v1 = (y[1] - mu) * inv * g4.y + b4.y;
  float v2 = (y[2] - mu) * inv * g4.z + b4.z;
  float v3 = (y[3] - mu) * inv * g4.w + b4.w;
  *(float4*)&out[(size_t)row * DD + c4] = make_float4(v0, v1, v2, v3);
  if (outb) {
    ushort4 ob; ob.x = f2bf(v0); ob.y = f2bf(v1); ob.z = f2bf(v2); ob.w = f2bf(v3);
    *(ushort4*)&outb[(row << 8) + ((t ^ ((row & 7) << 1)) << 2)] = ob;
  }
}

// ---------------- MFMA flash attention (32x32 QK, 64 q-rows/wave) ----------------
// 256 q-rows/block (4 waves x 64 = 2 q-tiles of 32). Every LDS K/V b128 read feeds
// TWO mfma (one per q-tile) -> LDS read demand halves vs round 7 (was the 38%
// MfmaUtil cap). ~450 VGPR -> 1 wave/SIMD, grid 256 blocks = 1/CU.
// No-max softmax (bounded log2 scores), P->A-frag via cvt_pk+permlane32_swap.
__global__ __launch_bounds__(256, 1) void flash_mfma_kernel(
    const ushort* __restrict__ qb, const ushort* __restrict__ kb,
    const ushort* __restrict__ vbT, ushort* __restrict__ opb,
    float* __restrict__ ml, int ksn, int kchunk)
{
  __shared__ ushort Kbuf[2][8192];   // [key 32][m 256] stored-swizzled (from kb)
  __shared__ ushort Vbuf[2][8192];   // [d 256][key 32], 16B-slot ^ ((d>>1)&3)

  const int tid = threadIdx.x;
  const int l = tid & 63, wv = tid >> 6;
  const int c32 = l & 31, hi = l >> 5;
  const int qt = blockIdx.x / ksn, ks = blockIdx.x % ksn;  // ks -> per-XCD KV chunk
  const int qA = qt * 256 + wv * 64;   // this wave's 64 q-rows
  const int kbase = ks * kchunk;

  const int vrow = tid >> 2;
  const ushort* kptr = kb + (size_t)(kbase + (tid >> 5)) * 256 + ((tid & 31) << 3);
  const ushort* vptr = vbT + (size_t)vrow * NN + kbase + (((tid & 3) ^ ((vrow >> 1) & 3)) << 3);

#define FSTAGE(b) { \
    _Pragma("unroll") \
    for (int c = 0; c < 4; ++c) { \
      async_copy16(&Kbuf[b][((c << 8) + tid) << 3], kptr + (size_t)c * (8 * 256)); \
      async_copy16(&Vbuf[b][((c << 8) + tid) << 3], vptr + (size_t)c * (64 * NN)); \
    } }

  FSTAGE(0)

  // Q fragments for both tiles: lane (q=c32) holds k-slice hi*8 of each 16-k block
  short8v qfr0[16], qfr1[16];
  {
    const ushort* qrowA = qb + (size_t)(qA + c32) * 256 + (hi << 3);
    const ushort* qrowB = qrowA + (size_t)32 * 256;
#pragma unroll
    for (int kk = 0; kk < 16; ++kk) {
      qfr0[kk] = *(const short8v*)(qrowA + (kk << 4));
      qfr1[kk] = *(const short8v*)(qrowB + (kk << 4));
    }
  }

  float16v acc0[8], acc1[8];
#pragma unroll
  for (int dt = 0; dt < 8; ++dt) { acc0[dt] = (float16v)(0.0f); acc1[dt] = (float16v)(0.0f); }
  float lsum0 = 0.f, lsum1 = 0.f;

  const int vsw = (c32 >> 1) & 3;
  const int voff0 = (hi ^ vsw) << 3;
  const int voff1 = ((2 + hi) ^ vsw) << 3;

  const int nit = kchunk >> 5;
  for (int it = 0; it < nit; ++it) {
    asm volatile("s_waitcnt vmcnt(0)" ::: "memory");
    __syncthreads();
    if (it + 1 < nit) {
      kptr += 32 * 256;
      vptr += 32;
      FSTAGE((it + 1) & 1)
    }
    const ushort* Kp = Kbuf[it & 1];
    const ushort* Vp = Vbuf[it & 1];

    // ---- S[key][q] = K @ Q^T for both q-tiles (each kf feeds 2 mfma) ----
    float16v s0 = (float16v)(0.0f), s1 = (float16v)(0.0f);
    __builtin_amdgcn_s_setprio(1);
#pragma unroll
    for (int kk = 0; kk < 16; ++kk) {
      short8v kf = *(const short8v*)&Kp[(c32 << 8) + (((kk << 4) + (hi << 3)) ^ ((c32 & 7) << 3))];
      s0 = __builtin_amdgcn_mfma_f32_32x32x16_bf16(kf, qfr0[kk], s0, 0, 0, 0);
      s1 = __builtin_amdgcn_mfma_f32_32x32x16_bf16(kf, qfr1[kk], s1, 0, 0, 0);
    }
    __builtin_amdgcn_s_setprio(0);

    // ---- softmax tile0 ----
    short8v P00, P01, P10, P11;
    {
      float p[16];
#pragma unroll
      for (int r = 0; r < 16; ++r) p[r] = exp2f(s0[r]);
      float t0 = (p[0] + p[1]) + (p[2] + p[3]);
      float t1 = (p[4] + p[5]) + (p[6] + p[7]);
      float t2 = (p[8] + p[9]) + (p[10] + p[11]);
      float t3 = (p[12] + p[13]) + (p[14] + p[15]);
      lsum0 += (t0 + t1) + (t2 + t3);
      unsigned u0, u1, u2, u3, u4, u5, u6, u7;
      asm("v_cvt_pk_bf16_f32 %0, %1, %2" : "=v"(u0) : "v"(p[0]),  "v"(p[1]));
      asm("v_cvt_pk_bf16_f32 %0, %1, %2" : "=v"(u1) : "v"(p[2]),  "v"(p[3]));
      asm("v_cvt_pk_bf16_f32 %0, %1, %2" : "=v"(u2) : "v"(p[4]),  "v"(p[5]));
      asm("v_cvt_pk_bf16_f32 %0, %1, %2" : "=v"(u3) : "v"(p[6]),  "v"(p[7]));
      asm("v_cvt_pk_bf16_f32 %0, %1, %2" : "=v"(u4) : "v"(p[8]),  "v"(p[9]));
      asm("v_cvt_pk_bf16_f32 %0, %1, %2" : "=v"(u5) : "v"(p[10]), "v"(p[11]));
      asm("v_cvt_pk_bf16_f32 %0, %1, %2" : "=v"(u6) : "v"(p[12]), "v"(p[13]));
      asm("v_cvt_pk_bf16_f32 %0, %1, %2" : "=v"(u7) : "v"(p[14]), "v"(p[15]));
      asm volatile("v_permlane32_swap_b32 %0, %1" : "+v"(u0), "+v"(u2));
      asm volatile("v_permlane32_swap_b32 %0, %1" : "+v"(u1), "+v"(u3));
      asm volatile("v_permlane32_swap_b32 %0, %1" : "+v"(u4), "+v"(u6));
      asm volatile("v_permlane32_swap_b32 %0, %1" : "+v"(u5), "+v"(u7));
      union { unsigned uu[4]; short8v v; } A, B;
      A.uu[0] = u0; A.uu[1] = u1; A.uu[2] = u2; A.uu[3] = u3;
      B.uu[0] = u4; B.uu[1] = u5; B.uu[2] = u6; B.uu[3] = u7;
      P00 = A.v; P01 = B.v;
    }
    // ---- softmax tile1 ----
    {
      float p[16];
#pragma unroll
      for (int r = 0; r < 16; ++r) p[r] = exp2f(s1[r]);
      float t0 = (p[0] + p[1]) + (p[2] + p[3]);
      float t1 = (p[4] + p[5]) + (p[6] + p[7]);
      float t2 = (p[8] + p[9]) + (p[10] + p[11]);
      float t3 = (p[12] + p[13]) + (p[14] + p[15]);
      lsum1 += (t0 + t1) + (t2 + t3);
      unsigned u0, u1, u2, u3, u4, u5, u6, u7;
      asm("v_cvt_pk_bf16_f32 %0, %1, %2" : "=v"(u0) : "v"(p[0]),  "v"(p[1]));
      asm("v_cvt_pk_bf16_f32 %0, %1, %2" : "=v"(u1) : "v"(p[2]),  "v"(p[3]));
      asm("v_cvt_pk_bf16_f32 %0, %1, %2" : "=v"(u2) : "v"(p[4]),  "v"(p[5]));
      asm("v_cvt_pk_bf16_f32 %0, %1, %2" : "=v"(u3) : "v"(p[6]),  "v"(p[7]));
      asm("v_cvt_pk_bf16_f32 %0, %1, %2" : "=v"(u4) : "v"(p[8]),  "v"(p[9]));
      asm("v_cvt_pk_bf16_f32 %0, %1, %2" : "=v"(u5) : "v"(p[10]), "v"(p[11]));
      asm("v_cvt_pk_bf16_f32 %0, %1, %2" : "=v"(u6) : "v"(p[12]), "v"(p[13]));
      asm("v_cvt_pk_bf16_f32 %0, %1, %2" : "=v"(u7) : "v"(p[14]), "v"(p[15]));
      asm volatile("v_permlane32_swap_b32 %0, %1" : "+v"(u0), "+v"(u2));
      asm volatile("v_permlane32_swap_b32 %0, %1" : "+v"(u1), "+v"(u3));
      asm volatile("v_permlane32_swap_b32 %0, %1" : "+v"(u4), "+v"(u6));
      asm volatile("v_permlane32_swap_b32 %0, %1" : "+v"(u5), "+v"(u7));
      union { unsigned uu[4]; short8v v; } A, B;
      A.uu[0] = u0; A.uu[1] = u1; A.uu[2] = u2; A.uu[3] = u3;
      B.uu[0] = u4; B.uu[1] = u5; B.uu[2] = u6; B.uu[3] = u7;
      P10 = A.v; P11 = B.v;
    }

    // ---- O += P @ V (each vf feeds 2 mfma) ----
    __builtin_amdgcn_s_setprio(1);
#pragma unroll
    for (int dt = 0; dt < 8; ++dt) {
      const int drow = (dt << 5) + c32;
      short8v vf0 = *(const short8v*)&Vp[(drow << 5) + voff0];
      short8v vf1 = *(const short8v*)&Vp[(drow << 5) + voff1];
      acc0[dt] = __builtin_amdgcn_mfma_f32_32x32x16_bf16(P00, vf0, acc0[dt], 0, 0, 0);
      acc1[dt] = __builtin_amdgcn_mfma_f32_32x32x16_bf16(P10, vf0, acc1[dt], 0, 0, 0);
      acc0[dt] = __builtin_amdgcn_mfma_f32_32x32x16_bf16(P01, vf1, acc0[dt], 0, 0, 0);
      acc1[dt] = __builtin_amdgcn_mfma_f32_32x32x16_bf16(P11, vf1, acc1[dt], 0, 0, 0);
    }
    __builtin_amdgcn_s_setprio(0);
  }
#undef FSTAGE

  // ---- epilogue: l reduce + bf16 partial stores ----
  float lt0 = lsum0 + __shfl_xor(lsum0, 32);
  float lt1 = lsum1 + __shfl_xor(lsum1, 32);
  if (hi == 0) {
    ml[(size_t)ks * NN + qA + c32] = lt0;
    ml[(size_t)ks * NN + qA + 32 + c32] = lt1;
  }
  ushort* op = opb + (size_t)ks * (NN * DD);
#pragma unroll
  for (int dt = 0; dt < 8; ++dt)
#pragma unroll
    for (int r = 0; r < 16; ++r) {
      const int ro = (r & 3) + ((r >> 2) << 3) + (hi << 2);
      op[(size_t)(qA + ro) * DD + (dt << 5) + c32] = f2bf(acc0[dt][r]);
      op[(size_t)(qA + 32 + ro) * DD + (dt << 5) + c32] = f2bf(acc1[dt][r]);
    }
}

// ---------------- merge (vectorized short8v, 8 rows/block) ----------------
__global__ __launch_bounds__(256) void flash_merge_kernel(
    const ushort* __restrict__ opb, const float* __restrict__ ml,
    ushort* __restrict__ hgb, int ksn)
{
  const int t = threadIdx.x;
  const int row = blockIdx.x * 8 + (t >> 5);
  const int cg = t & 31;
  float num[8] = {0.f, 0.f, 0.f, 0.f, 0.f, 0.f, 0.f, 0.f};
  float L = 0.f;
  for (int i = 0; i < ksn; ++i) {
    L += ml[(size_t)i * NN + row];
    short8v v = *(const short8v*)&opb[(size_t)i * NN * DD + (size_t)row * DD + (cg << 3)];
#pragma unroll
    for (int j = 0; j < 8; ++j) num[j] += b2f((ushort)v[j]);
  }
  float inv = 1.0f / L;
  short8v o;
#pragma unroll
  for (int j = 0; j < 8; ++j) o[j] = (short)f2bf(num[j] * inv);
  *(short8v*)&hgb[(row << 8) + ((cg ^ (row & 7)) << 3)] = o;
}

extern "C" void kernel_launch(void* const* d_in, const int* in_sizes, int n_in,
                              void* d_out, int out_size, void* d_ws, size_t ws_size,
                              hipStream_t stream) {
  (void)in_sizes; (void)n_in; (void)out_size;
  const float* h     = (const float*)d_in[0];
  const int*   ei    = (const int*)  d_in[1];
  const float* W_gcn = (const float*)d_in[2];
  const float* b_gcn = (const float*)d_in[3];
  const float* Wq    = (const float*)d_in[4];
  const float* bq    = (const float*)d_in[5];
  const float* Wk    = (const float*)d_in[6];
  const float* bk    = (const float*)d_in[7];
  const float* Wv    = (const float*)d_in[8];
  const float* bv    = (const float*)d_in[9];
  const float* Wo    = (const float*)d_in[10];
  const float* bo    = (const float*)d_in[11];
  const float* RF    = (const float*)d_in[12];
  const float* g1    = (const float*)d_in[13];
  const float* be1   = (const float*)d_in[14];
  const float* g2    = (const float*)d_in[15];
  const float* be2   = (const float*)d_in[16];
  const float* g3    = (const float*)d_in[17];
  const float* be3   = (const float*)d_in[18];
  const float* W1    = (const float*)d_in[19];
  const float* b1    = (const float*)d_in[20];
  const float* W2    = (const float*)d_in[21];
  const float* b2    = (const float*)d_in[22];
  float* out = (float*)d_out;

  const size_t M2 = (size_t)NN * DD;
  const int ksn = (ws_size >= (size_t)64 * 1024 * 1024) ? 8 : 4;
  const int kchunk = NN / ksn;

  char* base = (char*)d_ws;
  float*  h1   = (float*)base;  base += M2 * 4;
  ushort* hbX  = (ushort*)base; base += M2 * 2;   // hb, later hgb
  ushort* h1bX = (ushort*)base; base += M2 * 2;   // h1b, later h2b
  ushort* qb   = (ushort*)base; base += M2 * 2;
  ushort* kb   = (ushort*)base; base += M2 * 2;
  ushort* vbT  = (ushort*)base; base += M2 * 2;
  ushort* opb  = (ushort*)base;
  float*  R    = (float*)opb;   base += (size_t)ksn * M2 * 2;
  float*  mlf  = (float*)base;  base += (size_t)8 * NN * 4;
  ushort* WgcnT = (ushort*)base; base += DD * DD * 2;
  ushort* Wcat  = (ushort*)base; base += (size_t)768 * DD * 2;
  ushort* WoT   = (ushort*)base; base += DD * DD * 2;
  ushort* W1T   = (ushort*)base; base += FF * DD * 2;
  ushort* W2T   = (ushort*)base; base += DD * FF * 2;
  float*  bcat  = (float*)base;  base += 768 * 4;
  float*  dinv  = (float*)base;  base += NN * 4;
  int* degi    = (int*)base; base += NN * 4;
  int* cursor  = (int*)base; base += NN * 4;
  int* csr_off = (int*)base; base += (NN + 4) * 4;
  int* csr_src = (int*)base; base += EE * 4;

  // aliases
  ushort* xwb = (ushort*)R;        // bf16 xw, pre-flash (R region is opb during flash)
  float*  hgo = R;                 // post-merge
  float*  h2  = R + M2;            // post-merge
  ushort* tb  = qb;                // spans qb+kb, post-flash (8192x512 bf16)
  float*  f2  = h1;                // post-LN2 (h1 dead after LN2)
  ushort* hgb = hbX;
  ushort* h2b = h1bX;

  // CSR build
  init_kernel<<<NN / 256, 256, 0, stream>>>(degi, cursor);
  count_kernel<<<EE / 256, 256, 0, stream>>>(ei, degi);
  scan_kernel<<<1, 1024, 0, stream>>>(degi, csr_off, dinv);
  fill_kernel<<<EE / 256, 256, 0, stream>>>(ei, csr_off, cursor, csr_src);

  // fused precompute
  prep_kernel<<<P1B + 514, 256, 0, stream>>>(
      h, W_gcn, Wv, Wo, W1, W2, bv, Wq, Wk, bq, bk, RF,
      hbX, WgcnT, Wcat, WoT, W1T, W2T, bcat);

  // xw = h @ W_gcn (bf16 plain out -> L2-resident gather source)
  gemm_bf16_kernel<4, false><<<dim3(DD / 64, NN / 64), 256, 0, stream>>>(
      hbX, WgcnT, nullptr, xwb, nullptr, nullptr, NN, DD, DD);
  // local GCN + LN1
  gcn_gather_ln_kernel<<<NN, 64, 0, stream>>>(xwb, h, dinv, csr_off, csr_src, b_gcn, g1, be1, h1, h1bX);
  // fused q/k/v projections (single GEMM, routed epilogue)
  gemm_bf16_kernel<3, false><<<dim3(768 / 64, NN / 64), 256, 0, stream>>>(
      h1bX, Wcat, bcat, qb, kb, vbT, NN, 768, DD);
  // attention (256 q-rows/block, 1 block/CU)
  flash_mfma_kernel<<<(NN / 256) * ksn, 256, 0, stream>>>(qb, kb, vbT, opb, mlf, ksn, kchunk);
  flash_merge_kernel<<<NN / 8, 256, 0, stream>>>(opb, mlf, hgb, ksn);
  // output projection + LN2
  gemm_bf16_kernel<0, false><<<dim3(DD / 64, NN / 64), 256, 0, stream>>>(
      hgb, WoT, bo, hgo, nullptr, nullptr, NN, DD, DD);
  ln_res_kernel<<<NN, 64, 0, stream>>>(h1, hgo, g2, be2, h2, h2b);
  // FFN + LN3
  gemm_bf16_kernel<1, true ><<<dim3(FF / 64, NN / 64), 256, 0, stream>>>(
      h2b, W1T, b1, tb, nullptr, nullptr, NN, FF, DD);
  gemm_bf16_kernel<0, false><<<dim3(DD / 64, NN / 64), 256, 0, stream>>>(
      tb, W2T, b2, f2, nullptr, nullptr, NN, DD, FF);
  ln_res_kernel<<<NN, 64, 0, stream>>>(h2, f2, g3, be3, out, nullptr);
}

// Round 9
// 258.247 us; speedup vs baseline: 1.1820x; 1.1068x over previous
//
#include <hip/hip_runtime.h>
#include <hip/hip_bf16.h>

#define NN 8192
#define EE 262144
#define DD 256
#define FF 512
#define MM 256

typedef __attribute__((ext_vector_type(8))) short short8v;
typedef __attribute__((ext_vector_type(4))) float float4v;
typedef __attribute__((ext_vector_type(16))) float float16v;

__device__ __forceinline__ ushort f2bf(float x) {
  union { float f; unsigned u; } c; c.f = x;
  unsigned r = (c.u + 0x7FFF + ((c.u >> 16) & 1)) >> 16;
  return (ushort)r;
}
__device__ __forceinline__ float b2f(ushort u) {
  union { unsigned u; float f; } c; c.u = ((unsigned)u) << 16;
  return c.f;
}
__device__ __forceinline__ void async_copy16(void* lds, const void* g) {
  __builtin_amdgcn_global_load_lds(
      (const __attribute__((address_space(1))) void*)g,
      (__attribute__((address_space(3))) void*)lds, 16, 0, 0);
}

// ---------------- CSR build ----------------
__global__ void init_kernel(int* degi, int* cursor) {
  int i = blockIdx.x * blockDim.x + threadIdx.x;
  if (i < NN) { degi[i] = 0; cursor[i] = 0; }
}

__global__ void count_kernel(const int* __restrict__ ei, int* __restrict__ degi) {
  int i = blockIdx.x * blockDim.x + threadIdx.x;
  if (i < EE) atomicAdd(&degi[ei[EE + i]], 1);
}

__global__ __launch_bounds__(1024) void scan_kernel(const int* __restrict__ degi,
                                                    int* __restrict__ csr_off,
                                                    float* __restrict__ dinv) {
  __shared__ int part[1024];
  int tid = threadIdx.x;
  int base = tid * 8;
  int loc[8], dv[8]; int s = 0;
#pragma unroll
  for (int i = 0; i < 8; ++i) { int d = degi[base + i]; dv[i] = d; loc[i] = s; s += d; }
  part[tid] = s;
  __syncthreads();
  for (int off = 1; off < 1024; off <<= 1) {
    int v = (tid >= off) ? part[tid - off] : 0;
    __syncthreads();
    part[tid] += v;
    __syncthreads();
  }
  int pre = (tid == 0) ? 0 : part[tid - 1];
#pragma unroll
  for (int i = 0; i < 8; ++i) {
    csr_off[base + i] = pre + loc[i];
    dinv[base + i] = rsqrtf((float)(dv[i] + 1));  // +1 self loop
  }
  if (tid == 1023) csr_off[NN] = part[1023];
}

__global__ void fill_kernel(const int* __restrict__ ei, const int* __restrict__ csr_off,
                            int* __restrict__ cursor, int* __restrict__ csr_src) {
  int i = blockIdx.x * blockDim.x + threadIdx.x;
  if (i < EE) {
    int d = ei[EE + i];
    int pos = csr_off[d] + atomicAdd(&cursor[d], 1);
    csr_src[pos] = ei[i];
  }
}

// ---------------- fused precompute: converts + RF folds ----------------
#define QSCALE 0.090168441f   // log2(e) / 16
#define P1B 9985              // ceil(2556160 / 256)
__global__ __launch_bounds__(256) void prep_kernel(
    const float* __restrict__ h, const float* __restrict__ W_gcn,
    const float* __restrict__ Wv, const float* __restrict__ Wo,
    const float* __restrict__ W1, const float* __restrict__ W2,
    const float* __restrict__ bv,
    const float* __restrict__ Wq, const float* __restrict__ Wk,
    const float* __restrict__ bq, const float* __restrict__ bk,
    const float* __restrict__ RF,
    ushort* __restrict__ hb, ushort* __restrict__ WgcnT, ushort* __restrict__ Wcat,
    ushort* __restrict__ WoT, ushort* __restrict__ W1T, ushort* __restrict__ W2T,
    float* __restrict__ bcat)
{
  __shared__ float wrow[DD];
  if (blockIdx.x < P1B) {
    int i = blockIdx.x * 256 + threadIdx.x;
    const int R0 = NN * DD;
    const int R1 = R0 + DD * DD;
    const int R2 = R1 + DD * DD;
    const int R3 = R2 + DD * DD;
    const int R4 = R3 + DD * FF;
    const int R5 = R4 + FF * DD;
    const int R6 = R5 + DD;
    if (i < R0) {
      int row = i >> 8, col = i & 255;
      hb[(row << 8) | (col ^ ((row & 7) << 3))] = f2bf(h[i]);
    } else if (i < R1) {
      int j = i - R0; int n = j >> 8, k = j & 255;
      WgcnT[(n << 8) | (k ^ ((n & 7) << 3))] = f2bf(W_gcn[k * DD + n]);
    } else if (i < R2) {
      int j = i - R1; int n = j >> 8, k = j & 255;
      Wcat[((512 + n) << 8) | (k ^ ((n & 7) << 3))] = f2bf(Wv[k * DD + n]);
    } else if (i < R3) {
      int j = i - R2; int n = j >> 8, k = j & 255;
      WoT[(n << 8) | (k ^ ((n & 7) << 3))] = f2bf(Wo[k * DD + n]);
    } else if (i < R4) {
      int j = i - R3; int n = j >> 8, k = j & 255;
      W1T[(n << 8) | (k ^ ((n & 7) << 3))] = f2bf(W1[k * FF + n]);
    } else if (i < R5) {
      int j = i - R4; int n = j >> 9, k = j & 511;
      W2T[n * FF + (k ^ ((n & 7) << 3))] = f2bf(W2[k * DD + n]);
    } else if (i < R6) {
      bcat[512 + (i - R5)] = bv[i - R5];
    }
  } else {
    const int b = blockIdx.x - P1B;   // 0..513
    const int m = threadIdx.x;
    if (b < 512) {
      const int d = b & 255;
      const float* W = (b < 256) ? Wq : Wk;
      const float alpha = (b < 256) ? QSCALE : 1.0f;
      wrow[m] = W[d * DD + m];
      __syncthreads();
      float s = 0.0f;
      for (int j = 0; j < DD; ++j) s = fmaf(RF[m * DD + j], wrow[j], s);
      s *= alpha;
      const int row = (b < 256) ? m : (256 + m);
      Wcat[(row << 8) | (d ^ ((m & 7) << 3))] = f2bf(s);
    } else {
      const float* bvec = (b == 512) ? bq : bk;
      const float alpha = (b == 512) ? QSCALE : 1.0f;
      float s = 0.0f;
      for (int j = 0; j < DD; ++j) s = fmaf(bvec[j], RF[m * DD + j], s);
      bcat[((b == 512) ? 0 : 256) + m] = s * alpha;
    }
  }
}

// ---------------- MFMA GEMM: C[M][N] = act(A @ BT^T + bias) ----------------
// OMODE: 0 = f32 out; 1 = bf16 swizzled; 3 = qkv route (qb PLAIN, kb 2-term sw, vbT^T); 4 = bf16 plain
template<int OMODE, bool RELU>
__global__ __launch_bounds__(256) void gemm_bf16_kernel(
    const ushort* __restrict__ A, const ushort* __restrict__ BT,
    const float* __restrict__ bias, void* __restrict__ Cv,
    void* __restrict__ Cv2, void* __restrict__ Cv3,
    int M, int N, int K)
{
  __shared__ ushort As[2][4096];
  __shared__ ushort Bs[2][4096];
  const int tid = threadIdx.x;
  const int l = tid & 63;
  const int wv = tid >> 6;
  const int lr = l & 15, lg = l >> 4;
  const int m0 = blockIdx.y * 64, n0 = blockIdx.x * 64;
  const int wm = (wv >> 1) * 32, wn = (wv & 1) * 32;
  const int r0 = tid >> 3, r1 = 32 + (tid >> 3);
  const int co = (tid & 7) << 3;
  float4v acc[2][2];
#pragma unroll
  for (int mt = 0; mt < 2; ++mt)
#pragma unroll
    for (int nt = 0; nt < 2; ++nt) acc[mt][nt] = (float4v){0.f, 0.f, 0.f, 0.f};

#define GSTAGE(b, k0) { \
    async_copy16(&As[b][(r0 << 6) + co], &A[(size_t)(m0 + r0) * K + (k0) + co]); \
    async_copy16(&As[b][(r1 << 6) + co], &A[(size_t)(m0 + r1) * K + (k0) + co]); \
    async_copy16(&Bs[b][(r0 << 6) + co], &BT[(size_t)(n0 + r0) * K + (k0) + co]); \
    async_copy16(&Bs[b][(r1 << 6) + co], &BT[(size_t)(n0 + r1) * K + (k0) + co]); }

  GSTAGE(0, 0)
  const int nk = K >> 6;
  for (int kt = 0; kt < nk; ++kt) {
    asm volatile("s_waitcnt vmcnt(0)" ::: "memory");
    __syncthreads();
    if (kt + 1 < nk) GSTAGE((kt + 1) & 1, (kt + 1) << 6)
    const ushort* as_ = As[kt & 1];
    const ushort* bs_ = Bs[kt & 1];
    __builtin_amdgcn_s_setprio(1);
#pragma unroll
    for (int h = 0; h < 2; ++h) {
      const int swo = (((h << 2) + lg) ^ (lr & 7)) << 3;
      short8v af[2], bfr[2];
#pragma unroll
      for (int mt = 0; mt < 2; ++mt)
        af[mt] = *(const short8v*)&as_[((wm + (mt << 4) + lr) << 6) + swo];
#pragma unroll
      for (int nt = 0; nt < 2; ++nt)
        bfr[nt] = *(const short8v*)&bs_[((wn + (nt << 4) + lr) << 6) + swo];
#pragma unroll
      for (int mt = 0; mt < 2; ++mt)
#pragma unroll
        for (int nt = 0; nt < 2; ++nt)
          acc[mt][nt] = __builtin_amdgcn_mfma_f32_16x16x32_bf16(af[mt], bfr[nt], acc[mt][nt], 0, 0, 0);
    }
    __builtin_amdgcn_s_setprio(0);
  }
#pragma unroll
  for (int nt = 0; nt < 2; ++nt) {
    const int col = n0 + wn + (nt << 4) + lr;
    const float bv = bias ? bias[col] : 0.0f;
#pragma unroll
    for (int mt = 0; mt < 2; ++mt)
#pragma unroll
      for (int r = 0; r < 4; ++r) {
        const int m = m0 + wm + (mt << 4) + (lg << 2) + r;
        float v = acc[mt][nt][r] + bv;
        if (RELU) v = fmaxf(v, 0.0f);
        if (OMODE == 0) {
          ((float*)Cv)[(size_t)m * N + col] = v;
        } else if (OMODE == 1) {
          ((ushort*)Cv)[(size_t)m * N + (col ^ ((m & 7) << 3))] = f2bf(v);
        } else if (OMODE == 4) {
          ((ushort*)Cv)[(size_t)m * N + col] = f2bf(v);
        } else {  // qkv route
          if (col < 256) {
            ((ushort*)Cv)[(size_t)m * 256 + col] = f2bf(v);                         // qb plain
          } else if (col < 512) {
            const int c2 = (col - 256) ^ ((m & 7) << 3) ^ (((m >> 3) & 3) << 6);    // kb 2-term swizzle
            ((ushort*)Cv2)[(size_t)m * 256 + c2] = f2bf(v);
          } else {
            ((ushort*)Cv3)[(size_t)(col - 512) * NN + m] = f2bf(v);
          }
        }
      }
  }
#undef GSTAGE
}

// ---------------- GCN gather + residual + LN1 (1 wave/row, vectorized) ----------------
__global__ __launch_bounds__(64) void gcn_gather_ln_kernel(
    const ushort* __restrict__ xwb, const float* __restrict__ h,
    const float* __restrict__ dinv, const int* __restrict__ csr_off,
    const int* __restrict__ csr_src, const float* __restrict__ b_gcn,
    const float* __restrict__ g1, const float* __restrict__ be1,
    float* __restrict__ h1, ushort* __restrict__ h1b)
{
  const int node = blockIdx.x;
  const int t = threadIdx.x;
  const int c4 = t << 2;
  const float di = dinv[node];
  const int e0 = csr_off[node], e1 = csr_off[node + 1];
  float acc[4] = {0.f, 0.f, 0.f, 0.f};
  for (int e = e0; e < e1; ++e) {
    int s = csr_src[e];
    float ds = dinv[s];
    ushort4 xv = *(const ushort4*)&xwb[(size_t)s * DD + c4];
    acc[0] = fmaf(b2f(xv.x), ds, acc[0]);
    acc[1] = fmaf(b2f(xv.y), ds, acc[1]);
    acc[2] = fmaf(b2f(xv.z), ds, acc[2]);
    acc[3] = fmaf(b2f(xv.w), ds, acc[3]);
  }
  ushort4 sv = *(const ushort4*)&xwb[(size_t)node * DD + c4];
  float4 hv = *(const float4*)&h[(size_t)node * DD + c4];
  float4 bg = *(const float4*)&b_gcn[c4];
  const float dii = di * di;
  float y[4];
  y[0] = fmaf(acc[0], di, b2f(sv.x) * dii) + bg.x + hv.x;
  y[1] = fmaf(acc[1], di, b2f(sv.y) * dii) + bg.y + hv.y;
  y[2] = fmaf(acc[2], di, b2f(sv.z) * dii) + bg.z + hv.z;
  y[3] = fmaf(acc[3], di, b2f(sv.w) * dii) + bg.w + hv.w;
  float s1 = (y[0] + y[1]) + (y[2] + y[3]);
  float s2 = (y[0]*y[0] + y[1]*y[1]) + (y[2]*y[2] + y[3]*y[3]);
#pragma unroll
  for (int m = 1; m <= 32; m <<= 1) { s1 += __shfl_xor(s1, m); s2 += __shfl_xor(s2, m); }
  float mu = s1 * (1.0f / 256.0f);
  float var = s2 * (1.0f / 256.0f) - mu * mu;
  float inv = rsqrtf(fmaxf(var, 0.0f) + 1e-5f);
  float4 g4 = *(const float4*)&g1[c4];
  float4 b4 = *(const float4*)&be1[c4];
  float v0 = (y[0] - mu) * inv * g4.x + b4.x;
  float v1 = (y[1] - mu) * inv * g4.y + b4.y;
  float v2 = (y[2] - mu) * inv * g4.z + b4.z;
  float v3 = (y[3] - mu) * inv * g4.w + b4.w;
  *(float4*)&h1[(size_t)node * DD + c4] = make_float4(v0, v1, v2, v3);
  ushort4 ob; ob.x = f2bf(v0); ob.y = f2bf(v1); ob.z = f2bf(v2); ob.w = f2bf(v3);
  *(ushort4*)&h1b[(node << 8) + ((t ^ ((node & 7) << 1)) << 2)] = ob;
}

// ---------------- residual + LN (1 wave/row, vectorized) ----------------
__global__ __launch_bounds__(64) void ln_res_kernel(
    const float* __restrict__ a, const float* __restrict__ b,
    const float* __restrict__ g, const float* __restrict__ be,
    float* __restrict__ out, ushort* __restrict__ outb)
{
  const int row = blockIdx.x;
  const int t = threadIdx.x;
  const int c4 = t << 2;
  float4 av = *(const float4*)&a[(size_t)row * DD + c4];
  float4 bv = *(const float4*)&b[(size_t)row * DD + c4];
  float y[4] = {av.x + bv.x, av.y + bv.y, av.z + bv.z, av.w + bv.w};
  float s1 = (y[0] + y[1]) + (y[2] + y[3]);
  float s2 = (y[0]*y[0] + y[1]*y[1]) + (y[2]*y[2] + y[3]*y[3]);
#pragma unroll
  for (int m = 1; m <= 32; m <<= 1) { s1 += __shfl_xor(s1, m); s2 += __shfl_xor(s2, m); }
  float mu = s1 * (1.0f / 256.0f);
  float var = s2 * (1.0f / 256.0f) - mu * mu;
  float inv = rsqrtf(fmaxf(var, 0.0f) + 1e-5f);
  float4 g4 = *(const float4*)&g[c4];
  float4 b4 = *(const float4*)&be[c4];
  float v0 = (y[0] - mu) * inv * g4.x + b4.x;
  float v1 = (y[1] - mu) * inv * g4.y + b4.y;
  float v2 = (y[2] - mu) * inv * g4.z + b4.z;
  float v3 = (y[3] - mu) * inv * g4.w + b4.w;
  *(float4*)&out[(size_t)row * DD + c4] = make_float4(v0, v1, v2, v3);
  if (outb) {
    ushort4 ob; ob.x = f2bf(v0); ob.y = f2bf(v1); ob.z = f2bf(v2); ob.w = f2bf(v3);
    *(ushort4*)&outb[(row << 8) + ((t ^ ((row & 7) << 1)) << 2)] = ob;
  }
}

// ---------------- MFMA flash attention (32x32 QK, no-max softmax) ----------------
// Round-7 structure (32 q-rows/wave, 128 VGPR, 2 blocks/CU) with FULL-rank bank
// swizzles: K chunk = (2kk+hi) ^ (row&31) via 2-term XOR (bits 3-5 + 6-7);
// V slot = logical ^ ((row>>3)&3) -> chunk = 4*(c32&7) + (hi ^ (c32>>3)).
// Both bijective over 32 bank-groups: 2 lanes/bank per wave = conflict-free.
__global__ __launch_bounds__(256, 2) void flash_mfma_kernel(
    const ushort* __restrict__ qb, const ushort* __restrict__ kb,
    const ushort* __restrict__ vbT, ushort* __restrict__ opb,
    float* __restrict__ ml, int ksn, int kchunk)
{
  __shared__ ushort Kbuf[2][8192];   // [key 32][m 256], 2-term swizzled (from kb)
  __shared__ ushort Vbuf[2][8192];   // [d 256][key 32], slot ^ ((d>>3)&3)

  const int tid = threadIdx.x;
  const int l = tid & 63, wv = tid >> 6;
  const int c32 = l & 31, hi = l >> 5;
  const int qt = blockIdx.x / ksn, ks = blockIdx.x % ksn;  // ks -> per-XCD KV chunk
  const int q0 = qt * 128;
  const int kbase = ks * kchunk;

  const int vrow = tid >> 2;
  const ushort* kptr = kb + (size_t)(kbase + (tid >> 5)) * 256 + ((tid & 31) << 3);
  const ushort* vptr = vbT + (size_t)vrow * NN + kbase + (((tid & 3) ^ ((vrow >> 3) & 3)) << 3);

#define FSTAGE(b) { \
    _Pragma("unroll") \
    for (int c = 0; c < 4; ++c) { \
      async_copy16(&Kbuf[b][((c << 8) + tid) << 3], kptr + (size_t)c * (8 * 256)); \
      async_copy16(&Vbuf[b][((c << 8) + tid) << 3], vptr + (size_t)c * (64 * NN)); \
    } }

  FSTAGE(0)

  // Q fragments: 32 q-rows/wave, lane (q=c32) holds k-slice hi*8 of each 16-k block
  short8v qfr[16];
  {
    const ushort* qrow = qb + (size_t)(q0 + wv * 32 + c32) * 256 + (hi << 3);
#pragma unroll
    for (int kk = 0; kk < 16; ++kk)
      qfr[kk] = *(const short8v*)(qrow + (kk << 4));
  }

  float16v acc[8];
#pragma unroll
  for (int dt = 0; dt < 8; ++dt) acc[dt] = (float16v)(0.0f);
  float lsum = 0.f;

  // K read swizzle: full-rank (row&7 into bits 3-5, row>>3 into bits 6-7)
  const int ksw = ((c32 & 7) << 3) | (((c32 >> 3) & 3) << 6);
  // V read-side slot swizzle
  const int vsw = (c32 >> 3) & 3;
  const int voff0 = (hi ^ vsw) << 3;
  const int voff1 = ((2 + hi) ^ vsw) << 3;

  const int nit = kchunk >> 5;
  for (int it = 0; it < nit; ++it) {
    asm volatile("s_waitcnt vmcnt(0)" ::: "memory");
    __syncthreads();
    if (it + 1 < nit) {
      kptr += 32 * 256;
      vptr += 32;
      FSTAGE((it + 1) & 1)
    }
    const ushort* Kp = Kbuf[it & 1];
    const ushort* Vp = Vbuf[it & 1];

    // ---- S[key][q] = K @ Q^T (32x32, k=256) ----
    float16v s = (float16v)(0.0f);
    __builtin_amdgcn_s_setprio(1);
#pragma unroll
    for (int kk = 0; kk < 16; ++kk) {
      short8v kf = *(const short8v*)&Kp[(c32 << 8) + (((kk << 4) + (hi << 3)) ^ ksw)];
      s = __builtin_amdgcn_mfma_f32_32x32x16_bf16(kf, qfr[kk], s, 0, 0, 0);
    }
    __builtin_amdgcn_s_setprio(0);

    // ---- p = exp2(s), deferred l, P->A-frag via cvt_pk + permlane32_swap ----
    float p[16];
#pragma unroll
    for (int r = 0; r < 16; ++r) p[r] = exp2f(s[r]);
    {
      float t0 = (p[0] + p[1]) + (p[2] + p[3]);
      float t1 = (p[4] + p[5]) + (p[6] + p[7]);
      float t2 = (p[8] + p[9]) + (p[10] + p[11]);
      float t3 = (p[12] + p[13]) + (p[14] + p[15]);
      lsum += (t0 + t1) + (t2 + t3);
    }
    unsigned u0, u1, u2, u3, u4, u5, u6, u7;
    asm("v_cvt_pk_bf16_f32 %0, %1, %2" : "=v"(u0) : "v"(p[0]),  "v"(p[1]));
    asm("v_cvt_pk_bf16_f32 %0, %1, %2" : "=v"(u1) : "v"(p[2]),  "v"(p[3]));
    asm("v_cvt_pk_bf16_f32 %0, %1, %2" : "=v"(u2) : "v"(p[4]),  "v"(p[5]));
    asm("v_cvt_pk_bf16_f32 %0, %1, %2" : "=v"(u3) : "v"(p[6]),  "v"(p[7]));
    asm("v_cvt_pk_bf16_f32 %0, %1, %2" : "=v"(u4) : "v"(p[8]),  "v"(p[9]));
    asm("v_cvt_pk_bf16_f32 %0, %1, %2" : "=v"(u5) : "v"(p[10]), "v"(p[11]));
    asm("v_cvt_pk_bf16_f32 %0, %1, %2" : "=v"(u6) : "v"(p[12]), "v"(p[13]));
    asm("v_cvt_pk_bf16_f32 %0, %1, %2" : "=v"(u7) : "v"(p[14]), "v"(p[15]));
    asm volatile("v_permlane32_swap_b32 %0, %1" : "+v"(u0), "+v"(u2));
    asm volatile("v_permlane32_swap_b32 %0, %1" : "+v"(u1), "+v"(u3));
    asm volatile("v_permlane32_swap_b32 %0, %1" : "+v"(u4), "+v"(u6));
    asm volatile("v_permlane32_swap_b32 %0, %1" : "+v"(u5), "+v"(u7));
    union { unsigned uu[4]; short8v v; } P0, P1;
    P0.uu[0] = u0; P0.uu[1] = u1; P0.uu[2] = u2; P0.uu[3] = u3;  // keys 0..15
    P1.uu[0] = u4; P1.uu[1] = u5; P1.uu[2] = u6; P1.uu[3] = u7;  // keys 16..31

    // ---- O[q][d] += P @ V (8 x 32x32x16, 2 k-halves) ----
    __builtin_amdgcn_s_setprio(1);
#pragma unroll
    for (int dt = 0; dt < 8; ++dt) {
      const int drow = (dt << 5) + c32;
      short8v vf0 = *(const short8v*)&Vp[(drow << 5) + voff0];
      short8v vf1 = *(const short8v*)&Vp[(drow << 5) + voff1];
      acc[dt] = __builtin_amdgcn_mfma_f32_32x32x16_bf16(P0.v, vf0, acc[dt], 0, 0, 0);
      acc[dt] = __builtin_amdgcn_mfma_f32_32x32x16_bf16(P1.v, vf1, acc[dt], 0, 0, 0);
    }
    __builtin_amdgcn_s_setprio(0);
  }
#undef FSTAGE

  // ---- epilogue: l reduce (one shfl) + bf16 partial store ----
  float lt = lsum + __shfl_xor(lsum, 32);
  if (hi == 0) ml[(size_t)ks * NN + q0 + wv * 32 + c32] = lt;
  ushort* op = opb + (size_t)ks * (NN * DD);
#pragma unroll
  for (int dt = 0; dt < 8; ++dt)
#pragma unroll
    for (int r = 0; r < 16; ++r) {
      const int qrow = q0 + wv * 32 + (r & 3) + ((r >> 2) << 3) + (hi << 2);
      op[(size_t)qrow * DD + (dt << 5) + c32] = f2bf(acc[dt][r]);
    }
}

// ---------------- merge (vectorized short8v, 8 rows/block) ----------------
__global__ __launch_bounds__(256) void flash_merge_kernel(
    const ushort* __restrict__ opb, const float* __restrict__ ml,
    ushort* __restrict__ hgb, int ksn)
{
  const int t = threadIdx.x;
  const int row = blockIdx.x * 8 + (t >> 5);
  const int cg = t & 31;
  float num[8] = {0.f, 0.f, 0.f, 0.f, 0.f, 0.f, 0.f, 0.f};
  float L = 0.f;
  for (int i = 0; i < ksn; ++i) {
    L += ml[(size_t)i * NN + row];
    short8v v = *(const short8v*)&opb[(size_t)i * NN * DD + (size_t)row * DD + (cg << 3)];
#pragma unroll
    for (int j = 0; j < 8; ++j) num[j] += b2f((ushort)v[j]);
  }
  float inv = 1.0f / L;
  short8v o;
#pragma unroll
  for (int j = 0; j < 8; ++j) o[j] = (short)f2bf(num[j] * inv);
  *(short8v*)&hgb[(row << 8) + ((cg ^ (row & 7)) << 3)] = o;
}

extern "C" void kernel_launch(void* const* d_in, const int* in_sizes, int n_in,
                              void* d_out, int out_size, void* d_ws, size_t ws_size,
                              hipStream_t stream) {
  (void)in_sizes; (void)n_in; (void)out_size;
  const float* h     = (const float*)d_in[0];
  const int*   ei    = (const int*)  d_in[1];
  const float* W_gcn = (const float*)d_in[2];
  const float* b_gcn = (const float*)d_in[3];
  const float* Wq    = (const float*)d_in[4];
  const float* bq    = (const float*)d_in[5];
  const float* Wk    = (const float*)d_in[6];
  const float* bk    = (const float*)d_in[7];
  const float* Wv    = (const float*)d_in[8];
  const float* bv    = (const float*)d_in[9];
  const float* Wo    = (const float*)d_in[10];
  const float* bo    = (const float*)d_in[11];
  const float* RF    = (const float*)d_in[12];
  const float* g1    = (const float*)d_in[13];
  const float* be1   = (const float*)d_in[14];
  const float* g2    = (const float*)d_in[15];
  const float* be2   = (const float*)d_in[16];
  const float* g3    = (const float*)d_in[17];
  const float* be3   = (const float*)d_in[18];
  const float* W1    = (const float*)d_in[19];
  const float* b1    = (const float*)d_in[20];
  const float* W2    = (const float*)d_in[21];
  const float* b2    = (const float*)d_in[22];
  float* out = (float*)d_out;

  const size_t M2 = (size_t)NN * DD;
  const int ksn = (ws_size >= (size_t)64 * 1024 * 1024) ? 8 : 4;
  const int kchunk = NN / ksn;

  char* base = (char*)d_ws;
  float*  h1   = (float*)base;  base += M2 * 4;
  ushort* hbX  = (ushort*)base; base += M2 * 2;   // hb, later hgb
  ushort* h1bX = (ushort*)base; base += M2 * 2;   // h1b, later h2b
  ushort* qb   = (ushort*)base; base += M2 * 2;
  ushort* kb   = (ushort*)base; base += M2 * 2;
  ushort* vbT  = (ushort*)base; base += M2 * 2;
  ushort* opb  = (ushort*)base;
  float*  R    = (float*)opb;   base += (size_t)ksn * M2 * 2;
  float*  mlf  = (float*)base;  base += (size_t)8 * NN * 4;
  ushort* WgcnT = (ushort*)base; base += DD * DD * 2;
  ushort* Wcat  = (ushort*)base; base += (size_t)768 * DD * 2;
  ushort* WoT   = (ushort*)base; base += DD * DD * 2;
  ushort* W1T   = (ushort*)base; base += FF * DD * 2;
  ushort* W2T   = (ushort*)base; base += DD * FF * 2;
  float*  bcat  = (float*)base;  base += 768 * 4;
  float*  dinv  = (float*)base;  base += NN * 4;
  int* degi    = (int*)base; base += NN * 4;
  int* cursor  = (int*)base; base += NN * 4;
  int* csr_off = (int*)base; base += (NN + 4) * 4;
  int* csr_src = (int*)base; base += EE * 4;

  // aliases
  ushort* xwb = (ushort*)R;        // bf16 xw, pre-flash (R region is opb during flash)
  float*  hgo = R;                 // post-merge
  float*  h2  = R + M2;            // post-merge
  ushort* tb  = qb;                // spans qb+kb, post-flash (8192x512 bf16)
  float*  f2  = h1;                // post-LN2 (h1 dead after LN2)
  ushort* hgb = hbX;
  ushort* h2b = h1bX;

  // CSR build
  init_kernel<<<NN / 256, 256, 0, stream>>>(degi, cursor);
  count_kernel<<<EE / 256, 256, 0, stream>>>(ei, degi);
  scan_kernel<<<1, 1024, 0, stream>>>(degi, csr_off, dinv);
  fill_kernel<<<EE / 256, 256, 0, stream>>>(ei, csr_off, cursor, csr_src);

  // fused precompute
  prep_kernel<<<P1B + 514, 256, 0, stream>>>(
      h, W_gcn, Wv, Wo, W1, W2, bv, Wq, Wk, bq, bk, RF,
      hbX, WgcnT, Wcat, WoT, W1T, W2T, bcat);

  // xw = h @ W_gcn (bf16 plain out -> L2-resident gather source)
  gemm_bf16_kernel<4, false><<<dim3(DD / 64, NN / 64), 256, 0, stream>>>(
      hbX, WgcnT, nullptr, xwb, nullptr, nullptr, NN, DD, DD);
  // local GCN + LN1
  gcn_gather_ln_kernel<<<NN, 64, 0, stream>>>(xwb, h, dinv, csr_off, csr_src, b_gcn, g1, be1, h1, h1bX);
  // fused q/k/v projections (single GEMM, routed epilogue)
  gemm_bf16_kernel<3, false><<<dim3(768 / 64, NN / 64), 256, 0, stream>>>(
      h1bX, Wcat, bcat, qb, kb, vbT, NN, 768, DD);
  // attention (128 q-rows/block, 2 blocks/CU)
  flash_mfma_kernel<<<(NN / 128) * ksn, 256, 0, stream>>>(qb, kb, vbT, opb, mlf, ksn, kchunk);
  flash_merge_kernel<<<NN / 8, 256, 0, stream>>>(opb, mlf, hgb, ksn);
  // output projection + LN2
  gemm_bf16_kernel<0, false><<<dim3(DD / 64, NN / 64), 256, 0, stream>>>(
      hgb, WoT, bo, hgo, nullptr, nullptr, NN, DD, DD);
  ln_res_kernel<<<NN, 64, 0, stream>>>(h1, hgo, g2, be2, h2, h2b);
  // FFN + LN3
  gemm_bf16_kernel<1, true ><<<dim3(FF / 64, NN / 64), 256, 0, stream>>>(
      h2b, W1T, b1, tb, nullptr, nullptr, NN, FF, DD);
  gemm_bf16_kernel<0, false><<<dim3(DD / 64, NN / 64), 256, 0, stream>>>(
      tb, W2T, b2, f2, nullptr, nullptr, NN, DD, FF);
  ln_res_kernel<<<NN, 64, 0, stream>>>(h2, f2, g3, be3, out, nullptr);
}